// Round 7
// baseline (508.891 us; speedup 1.0000x reference)
//
#include <hip/hip_runtime.h>
#include <hip/hip_bf16.h>
#include <math.h>

#define ROWS 16384   // B*N = 8*2048

typedef _Float16 f16x8 __attribute__((ext_vector_type(8)));
typedef _Float16 f16x4 __attribute__((ext_vector_type(4)));
typedef float f32x4 __attribute__((ext_vector_type(4)));

// ---- workspace offsets (floats); total identical to proven 31,330,304 ----
static const size_t OFF_OVL = 0;            // 16384*512 fp32 overlap
static const size_t OFF_HID = 8388608;      // 16384*128 fp32
static const size_t OFF_N2  = 10485760;     // 16384*8
static const size_t OFF_VG  = 10616832;     // 512*8
static const size_t OFF_MRE = 10620928;     // 65536
static const size_t OFF_MIM = 10686464;     // 65536
static const size_t OFF_VWH = 10752000;     // 512*1024 f16 = 262144 fl
static const size_t OFF_VWL = 11014144;     // 262144 fl
static const size_t OFF_BH  = 11276288;     // 1024*3200 f16 = 1638400 fl
static const size_t OFF_BL  = 12914688;     // 1638400 fl
static const size_t OFF_AH  = 14553088;     // 16384*1024 f16 = 8388608 fl; early: VW fp32; late: WH alias
static const size_t OFF_AL  = 22941696;     // 8388608 fl; late: WL alias
static const size_t WS_FLOATS = 31330304;   // 125.32 MB

__device__ __forceinline__ void gload_lds16(const void* g, void* l) {
  __builtin_amdgcn_global_load_lds((const __attribute__((address_space(1))) void*)g,
                                   (__attribute__((address_space(3))) void*)l, 16, 0, 0);
}

__device__ __forceinline__ void split16(float v, _Float16& hi, _Float16& lo) {
  _Float16 h = (_Float16)v;
  hi = h;
  lo = (_Float16)(v - (float)h);
}

// ---------------- prep: normalize memory states ----------------
__global__ void k_prep_mem(const float* __restrict__ mr, const float* __restrict__ mi,
                           float* __restrict__ mReN, float* __restrict__ mImN) {
  int hs = blockIdx.x;
  int t  = threadIdx.x;
  const float* pr = mr + (size_t)hs * 128;
  const float* pi = mi + (size_t)hs * 128;
  float a0 = pr[t], a1 = pr[t + 64], b0 = pi[t], b1 = pi[t + 64];
  float ss = a0*a0 + a1*a1 + b0*b0 + b1*b1;
  #pragma unroll
  for (int off = 1; off < 64; off <<= 1) ss += __shfl_xor(ss, off);
  float inv = 1.f / fmaxf(sqrtf(ss), 1e-12f);
  mReN[(size_t)hs*128 + t]      = a0 * inv;
  mReN[(size_t)hs*128 + t + 64] = a1 * inv;
  mImN[(size_t)hs*128 + t]      = b0 * inv;
  mImN[(size_t)hs*128 + t + 64] = b1 * inv;
}

// ---------------- prep: VG[h,s,g] ----------------
__global__ __launch_bounds__(256) void k_prep_vg(const float* __restrict__ vals,
                                                 const float* __restrict__ gw,
                                                 float* __restrict__ VG) {
  int hs = blockIdx.x;
  int h  = hs >> 6;
  int t  = threadIdx.x;
  float acc[8] = {0,0,0,0,0,0,0,0};
  for (int dd = t; dd < 1024; dd += 256) {
    float v = vals[(size_t)hs*1024 + dd];
    const float* g = gw + (size_t)(h*1024 + dd)*8;
    #pragma unroll
    for (int q = 0; q < 8; ++q) acc[q] += v * g[q];
  }
  #pragma unroll
  for (int off = 1; off < 64; off <<= 1)
    #pragma unroll
    for (int q = 0; q < 8; ++q) acc[q] += __shfl_xor(acc[q], off);
  __shared__ float red[4][8];
  if ((t & 63) == 0) {
    #pragma unroll
    for (int q = 0; q < 8; ++q) red[t >> 6][q] = acc[q];
  }
  __syncthreads();
  if (t < 8) VG[(size_t)hs*8 + t] = red[0][t] + red[1][t] + red[2][t] + red[3][t];
}

// ---------------- prep: Wr/Wi/pw1 -> BH/BL fragment tiles directly ----------------
__global__ __launch_bounds__(256) void k_prep_b16(const float* __restrict__ Wr,
                                                  const float* __restrict__ Wi,
                                                  const float* __restrict__ pw1,
                                                  _Float16* __restrict__ BH,
                                                  _Float16* __restrict__ BL) {
  int g = blockIdx.x * 256 + threadIdx.x;   // 128*2176 = 278528 total
  int c  = g % 2176;
  int k0 = g / 2176;                        // 0..127 (8 consecutive k)
  float v[8];
  if (c < 1024) {
    int h = c >> 7, e = c & 127;
    const float* p = Wr + ((size_t)(h << 10) + k0*8) * 128 + e;
    #pragma unroll
    for (int j = 0; j < 8; ++j) v[j] = p[(size_t)j*128];
  } else if (c < 2048) {
    int c2 = c - 1024; int h = c2 >> 7, e = c2 & 127;
    const float* p = Wi + ((size_t)(h << 10) + k0*8) * 128 + e;
    #pragma unroll
    for (int j = 0; j < 8; ++j) v[j] = p[(size_t)j*128];
  } else {
    int q = c - 2048; int h = q >> 4, kk = q & 15;
    const float* p = pw1 + ((size_t)(h << 10) + k0*8) * 16 + kk;
    #pragma unroll
    for (int j = 0; j < 8; ++j) v[j] = p[(size_t)j*16];
  }
  int Bcol = (c < 2048) ? c : 3072 + (c - 2048);
  int nt = Bcol >> 7, c8 = (Bcol >> 4) & 7, c15 = Bcol & 15;
  int kt = k0 >> 2, kg = k0 & 3;
  size_t base = ((size_t)nt*32 + kt)*4096 + c8*512 + kg*128 + c15*8;
  f16x8 hv, lv;
  #pragma unroll
  for (int j = 0; j < 8; ++j) { _Float16 hi, lo; split16(v[j], hi, lo); hv[j] = hi; lv[j] = lo; }
  *(f16x8*)(BH + base) = hv;
  *(f16x8*)(BL + base) = lv;
}

// ---------------- prep: Aov -> BH/BL fragment tiles (nt 16..23) ----------------
__global__ __launch_bounds__(256) void k_prep_aov16(const float* __restrict__ Wr,
                                                    const float* __restrict__ Wi,
                                                    const float* __restrict__ mReN,
                                                    const float* __restrict__ mImN,
                                                    _Float16* __restrict__ BH,
                                                    _Float16* __restrict__ BL) {
  int bid = blockIdx.x;          // h(8) x kt64(16) x shalf(2)
  int h   = bid >> 5;
  int kt64 = (bid >> 1) & 15;
  int sh  = bid & 1;
  __shared__ float sRe[32][129];
  __shared__ float sIm[32][129];
  int tid = threadIdx.x;
  int s0 = sh * 32;
  for (int i = tid; i < 32 * 32; i += 256) {
    int s = i >> 5; int e4 = (i & 31) << 2;
    *(float4*)&sRe[s][e4] = *(const float4*)(mReN + ((size_t)(h*64 + s0 + s)*128 + e4));
    *(float4*)&sIm[s][e4] = *(const float4*)(mImN + ((size_t)(h*64 + s0 + s)*128 + e4));
  }
  __syncthreads();
  int kq = tid >> 5;
  int s  = tid & 31;
  int kbase = kt64*64 + kq*8;
  float aR[8] = {0,0,0,0,0,0,0,0}, aI[8] = {0,0,0,0,0,0,0,0};
  for (int e0 = 0; e0 < 128; e0 += 4) {
    float4 mre = *(float4*)&sRe[s][e0];
    float4 mim = *(float4*)&sIm[s][e0];
    #pragma unroll
    for (int j = 0; j < 8; ++j) {
      const float4 wr = *(const float4*)(Wr + ((size_t)(h*1024 + kbase + j))*128 + e0);
      const float4 wi = *(const float4*)(Wi + ((size_t)(h*1024 + kbase + j))*128 + e0);
      aR[j] += wr.x*mre.x + wr.y*mre.y + wr.z*mre.z + wr.w*mre.w
             + wi.x*mim.x + wi.y*mim.y + wi.z*mim.z + wi.w*mim.w;
      aI[j] += wi.x*mre.x + wi.y*mre.y + wi.z*mre.z + wi.w*mre.w
             - (wr.x*mim.x + wr.y*mim.y + wr.z*mim.z + wr.w*mim.w);
    }
  }
  int kt32 = kbase >> 5;
  int kg   = (kbase >> 3) & 3;
  int coln = s0 + s;
  size_t baseR = ((size_t)(16 + h)*32 + kt32)*4096 + (size_t)(coln >> 4)*512 + kg*128 + (coln & 15)*8;
  size_t baseI = baseR + 4*512;
  f16x8 hR, lR, hI, lI;
  #pragma unroll
  for (int j = 0; j < 8; ++j) {
    _Float16 hi, lo;
    split16(aR[j], hi, lo); hR[j] = hi; lR[j] = lo;
    split16(aI[j], hi, lo); hI[j] = hi; lI[j] = lo;
  }
  *(f16x8*)(BH + baseR) = hR; *(f16x8*)(BL + baseR) = lR;
  *(f16x8*)(BH + baseI) = hI; *(f16x8*)(BL + baseI) = lI;
}

// ---------------- VW = values_flat(512x1024) @ out_w(1024x1024), fp32 ----------------
__global__ __launch_bounds__(256) void k_gemm64(const float* __restrict__ A,
                                                const float* __restrict__ B,
                                                float* __restrict__ C,
                                                int K, int lda, int ldb, int ldc) {
  __shared__ float As[16][64];
  __shared__ float Bs[16][64];
  int tid = threadIdx.x;
  int tm = tid >> 4, tn = tid & 15;
  float acc[4][4];
  #pragma unroll
  for (int i = 0; i < 4; ++i)
    #pragma unroll
    for (int j = 0; j < 4; ++j) acc[i][j] = 0.f;
  int row0 = blockIdx.y << 6, col0 = blockIdx.x << 6;
  int ar = tid >> 2, ak = (tid & 3) << 2;
  int bkr = tid >> 4, bc = (tid & 15) << 2;
  for (int kt = 0; kt < K; kt += 16) {
    float4 a0 = *(const float4*)(A + (size_t)(row0 + ar)*lda + kt + ak);
    float4 b0 = *(const float4*)(B + (size_t)(kt + bkr)*ldb + col0 + bc);
    __syncthreads();
    As[ak+0][ar] = a0.x; As[ak+1][ar] = a0.y; As[ak+2][ar] = a0.z; As[ak+3][ar] = a0.w;
    *(float4*)&Bs[bkr][bc] = b0;
    __syncthreads();
    #pragma unroll
    for (int k = 0; k < 16; ++k) {
      float af[4], bf[4];
      *(float4*)&af[0] = *(const float4*)&As[k][tm << 2];
      *(float4*)&bf[0] = *(const float4*)&Bs[k][tn << 2];
      #pragma unroll
      for (int i = 0; i < 4; ++i)
        #pragma unroll
        for (int j = 0; j < 4; ++j) acc[i][j] += af[i] * bf[j];
    }
  }
  #pragma unroll
  for (int i = 0; i < 4; ++i) {
    float4 v; v.x = acc[i][0]; v.y = acc[i][1]; v.z = acc[i][2]; v.w = acc[i][3];
    *(float4*)(C + (size_t)(row0 + (tm << 2) + i)*ldc + col0 + (tn << 2)) = v;
  }
}

// ---------------- convA: h (16384x1024 fp32) -> hi/lo fragment tiles, vectorized ----------------
// float4-coalesced reads; 8B f16x4 stores. grid 4096 x 256, 4 float4/thread.
__global__ __launch_bounds__(256) void k_convA(const float* __restrict__ src,
                                               _Float16* __restrict__ dh, _Float16* __restrict__ dl) {
  int f0 = blockIdx.x * 256 + threadIdx.x;
  #pragma unroll
  for (int i = 0; i < 4; ++i) {
    int f = f0 + i * 1048576;                 // float4 index over 16384x256
    int row = f >> 8, k4 = f & 255;
    int mt = row >> 7, r8 = (row >> 4) & 7, r15 = row & 15;
    int kt = k4 >> 3, kg = (k4 >> 1) & 3, j0 = (k4 & 1) << 2;
    size_t base = ((size_t)(mt*32 + kt))*4096 + r8*512 + kg*128 + r15*8 + j0;
    float4 v = ((const float4*)src)[f];
    _Float16 h0, l0, h1, l1, h2, l2, h3, l3;
    split16(v.x, h0, l0);
    split16(v.y, h1, l1);
    split16(v.z, h2, l2);
    split16(v.w, h3, l3);
    f16x4 hv, lv;
    hv[0] = h0; hv[1] = h1; hv[2] = h2; hv[3] = h3;
    lv[0] = l0; lv[1] = l1; lv[2] = l2; lv[3] = l3;
    *(f16x4*)(dh + base) = hv;
    *(f16x4*)(dl + base) = lv;
  }
}

// B-side conversion (used for VW only)
__global__ __launch_bounds__(256) void k_convB(const float* __restrict__ src, int ldb, int ktiles,
                                               _Float16* __restrict__ dh, _Float16* __restrict__ dl) {
  int nt = blockIdx.x / ktiles, kt = blockIdx.x % ktiles;
  size_t base = (size_t)blockIdx.x * 4096;
  for (int q = 0; q < 16; ++q) {
    int i = q*256 + threadIdx.x;
    int c8 = i >> 9, kg = (i >> 7) & 3, c15 = (i >> 3) & 15, j = i & 7;
    int col = nt*128 + c8*16 + c15;
    int k   = kt*32 + kg*8 + j;
    float v = src[(size_t)k*ldb + col];
    _Float16 hi, lo; split16(v, hi, lo);
    dh[base + i] = hi; dl[base + i] = lo;
  }
}

// ---------------- norm GEMM: hi-only, 128x128, double-buffered pipeline ----------------
__global__ __launch_bounds__(256) void k_qnorm(const _Float16* __restrict__ Ah,
                                               const _Float16* __restrict__ Bh,
                                               float* __restrict__ n2) {
  __shared__ __align__(16) char smem[32768];
  const int id = blockIdx.x;
  const int by = (id & 7) * 16 + ((id >> 3) & 15);
  const int bx = id >> 7;                      // 0..15
  const int tid = threadIdx.x;
  const int wid = tid >> 6, lane = tid & 63;
  const int wr = wid >> 1, wc = wid & 1;
  const char* gA = (const char*)Ah + (size_t)by * 32 * 8192;
  const char* gB = (const char*)Bh + (size_t)bx * 32 * 8192;

  f32x4 acc[4][4];
  #pragma unroll
  for (int i = 0; i < 4; ++i)
    #pragma unroll
    for (int j = 0; j < 4; ++j) acc[i][j] = (f32x4){0.f,0.f,0.f,0.f};

  auto stage = [&](int b, int kt) {
    const char* srcA = gA + (size_t)kt * 8192;
    const char* srcB = gB + (size_t)kt * 8192;
    char* dA = smem + b * 8192;
    char* dB = smem + 16384 + b * 8192;
    #pragma unroll
    for (int q = 0; q < 4; ++q) {
      int c = wid * 4 + q;
      int sub = (c & 7) * 1024;
      if (c < 8) gload_lds16(srcA + sub + lane*16, dA + sub);
      else       gload_lds16(srcB + sub + lane*16, dB + sub);
    }
  };

  stage(0, 0);
  asm volatile("s_waitcnt vmcnt(0)" ::: "memory");
  __builtin_amdgcn_s_barrier();
  int cur = 0;
  for (int kt = 0; kt < 32; ++kt) {
    if (kt < 31) stage(cur ^ 1, kt + 1);
    const char* cA = smem + cur * 8192;
    const char* cB = smem + 16384 + cur * 8192;
    f16x8 a[4], b[4];
    #pragma unroll
    for (int m = 0; m < 4; ++m) a[m] = *(const f16x8*)(cA + wr*4096 + m*1024 + lane*16);
    #pragma unroll
    for (int n = 0; n < 4; ++n) b[n] = *(const f16x8*)(cB + wc*4096 + n*1024 + lane*16);
    #pragma unroll
    for (int m = 0; m < 4; ++m)
      #pragma unroll
      for (int n = 0; n < 4; ++n)
        acc[m][n] = __builtin_amdgcn_mfma_f32_16x16x32_f16(a[m], b[n], acc[m][n], 0, 0, 0);
    if (kt < 31) {
      asm volatile("s_waitcnt vmcnt(0)" ::: "memory");
      __builtin_amdgcn_s_barrier();
    }
    cur ^= 1;
  }

  const int head = bx & 7;
  #pragma unroll
  for (int m = 0; m < 4; ++m)
    #pragma unroll
    for (int rr = 0; rr < 4; ++rr) {
      float rs = 0.f;
      #pragma unroll
      for (int n = 0; n < 4; ++n) rs += acc[m][n][rr] * acc[m][n][rr];
      rs += __shfl_xor(rs, 1); rs += __shfl_xor(rs, 2);
      rs += __shfl_xor(rs, 4); rs += __shfl_xor(rs, 8);
      if ((lane & 15) == 0) {
        int row = by*128 + wr*64 + m*16 + (lane >> 4)*4 + rr;
        atomicAdd(&n2[(size_t)row*8 + head], rs);
      }
    }
}

// ---------------- value GEMM: 3-term, 128x128, double-buffered (bx<8: OV head, bx==8: HID) ----------------
__global__ __launch_bounds__(256) void k_qval(const _Float16* __restrict__ Ah,
                                              const _Float16* __restrict__ Al,
                                              const _Float16* __restrict__ Bh,
                                              const _Float16* __restrict__ Bl,
                                              float* __restrict__ OVL,
                                              float* __restrict__ HID) {
  __shared__ __align__(16) char smem[65536];   // 2 bufs x {Ah,Al,Bh,Bl} x 8KB
  const int id = blockIdx.x;
  const int rest = id >> 3;
  const int by = (id & 7) * 16 + (rest & 15);
  const int bx = rest >> 4;                    // 0..8
  const int tid = threadIdx.x;
  const int wid = tid >> 6, lane = tid & 63;
  const int wr = wid >> 1, wc = wid & 1;
  f32x4 acc[4][4];
  #pragma unroll
  for (int i = 0; i < 4; ++i)
    #pragma unroll
    for (int j = 0; j < 4; ++j) acc[i][j] = (f32x4){0.f,0.f,0.f,0.f};

  const char* pAh = (const char*)Ah + (size_t)by*32*8192;
  const char* pAl = (const char*)Al + (size_t)by*32*8192;
  const char* pBh = (const char*)Bh + (size_t)(16 + bx)*32*8192;
  const char* pBl = (const char*)Bl + (size_t)(16 + bx)*32*8192;
  // wave wid owns one matrix stream (uniform LDS dst base, per-lane global src)
  const char* mysrc = (wid == 0) ? pAh : (wid == 1) ? pAl : (wid == 2) ? pBh : pBl;

  auto stage = [&](int b, int kt) {
    const char* s = mysrc + (size_t)kt*8192 + lane*16;
    char* d = smem + b*32768 + wid*8192;
    #pragma unroll
    for (int q = 0; q < 8; ++q)
      gload_lds16(s + q*1024, d + q*1024);
  };

  stage(0, 0);
  asm volatile("s_waitcnt vmcnt(0)" ::: "memory");
  __builtin_amdgcn_s_barrier();
  int cur = 0;
  for (int kt = 0; kt < 32; ++kt) {
    if (kt < 31) stage(cur ^ 1, kt + 1);
    const char* base = smem + cur*32768;
    const char* cAh = base;
    const char* cAl = base + 8192;
    const char* cBh = base + 16384;
    const char* cBl = base + 24576;
    f16x8 a_h[4], a_l[4], b_h[4], b_l[4];
    #pragma unroll
    for (int m = 0; m < 4; ++m) { a_h[m] = *(const f16x8*)(cAh + wr*4096 + m*1024 + lane*16);
                                  a_l[m] = *(const f16x8*)(cAl + wr*4096 + m*1024 + lane*16); }
    #pragma unroll
    for (int n = 0; n < 4; ++n) { b_h[n] = *(const f16x8*)(cBh + wc*4096 + n*1024 + lane*16);
                                  b_l[n] = *(const f16x8*)(cBl + wc*4096 + n*1024 + lane*16); }
    #pragma unroll
    for (int m = 0; m < 4; ++m)
      #pragma unroll
      for (int n = 0; n < 4; ++n) {
        acc[m][n] = __builtin_amdgcn_mfma_f32_16x16x32_f16(a_h[m], b_h[n], acc[m][n], 0, 0, 0);
        acc[m][n] = __builtin_amdgcn_mfma_f32_16x16x32_f16(a_l[m], b_h[n], acc[m][n], 0, 0, 0);
        acc[m][n] = __builtin_amdgcn_mfma_f32_16x16x32_f16(a_h[m], b_l[n], acc[m][n], 0, 0, 0);
      }
    if (kt < 31) {
      asm volatile("s_waitcnt vmcnt(0)" ::: "memory");
      __builtin_amdgcn_s_barrier();
    }
    cur ^= 1;
  }
  __syncthreads();   // all waves done with LDS buffers before epilogue reuse

  if (bx == 8) {
    #pragma unroll
    for (int m = 0; m < 4; ++m)
      #pragma unroll
      for (int n = 0; n < 4; ++n)
        #pragma unroll
        for (int rr = 0; rr < 4; ++rr) {
          int row = by*128 + wr*64 + m*16 + (lane>>4)*4 + rr;
          int col = wc*64 + n*16 + (lane&15);
          HID[(size_t)row*128 + col] = acc[m][n][rr];
        }
  } else {
    float* sOv = (float*)smem;   // [128][68]
    if (wc == 0) {
      #pragma unroll
      for (int m = 0; m < 4; ++m)
        #pragma unroll
        for (int n = 0; n < 4; ++n)
          #pragma unroll
          for (int rr = 0; rr < 4; ++rr) {
            int r128 = wr*64 + m*16 + (lane>>4)*4 + rr;
            int s = n*16 + (lane&15);
            sOv[r128*68 + s] = acc[m][n][rr]*acc[m][n][rr];
          }
    }
    __syncthreads();
    if (wc == 1) {
      #pragma unroll
      for (int m = 0; m < 4; ++m)
        #pragma unroll
        for (int n = 0; n < 4; ++n)
          #pragma unroll
          for (int rr = 0; rr < 4; ++rr) {
            int r128 = wr*64 + m*16 + (lane>>4)*4 + rr;
            int s = n*16 + (lane&15);
            float v = sOv[r128*68 + s] + acc[m][n][rr]*acc[m][n][rr];
            int row = by*128 + r128;
            OVL[(size_t)row*512 + bx*64 + s] = v;
          }
    }
  }
}

// ---------------- final MFMA GEMM: out = wattn(16384x512) @ VW(512x1024) + out_b ----------------
__global__ __launch_bounds__(256) void k_fin(const _Float16* __restrict__ Ahh,
                                             const _Float16* __restrict__ Alo,
                                             const _Float16* __restrict__ Bhh,
                                             const _Float16* __restrict__ Blo,
                                             const float* __restrict__ bias,
                                             float* __restrict__ out) {
  __shared__ __align__(16) char smem[32768];
  const int bx = blockIdx.x;   // 0..7
  const int by = blockIdx.y;   // 0..127
  const int tid = threadIdx.x;
  const int wid = tid >> 6, lane = tid & 63;
  const int wr = wid >> 1, wc = wid & 1;
  char* sAh = smem;
  char* sAl = smem + 8192;
  char* sBh = smem + 16384;
  char* sBl = smem + 24576;
  f32x4 acc[4][4];
  #pragma unroll
  for (int i = 0; i < 4; ++i)
    #pragma unroll
    for (int j = 0; j < 4; ++j) acc[i][j] = (f32x4){0.f,0.f,0.f,0.f};
  const char* gAh = (const char*)Ahh + (size_t)by*16*8192;
  const char* gAl = (const char*)Alo + (size_t)by*16*8192;
  const char* gBh = (const char*)Bhh + (size_t)bx*16*8192;
  const char* gBl = (const char*)Blo + (size_t)bx*16*8192;
  const int soff = wid*2048;
  const int lsrc = soff + lane*16;
  const int aoff = wr*4096 + lane*16;
  const int boff = wc*4096 + lane*16;
  for (int kt = 0; kt < 16; ++kt) {
    const size_t tb = (size_t)kt*8192;
    gload_lds16(gAh + tb + lsrc,        sAh + soff);
    gload_lds16(gAh + tb + lsrc + 1024, sAh + soff + 1024);
    gload_lds16(gBh + tb + lsrc,        sBh + soff);
    gload_lds16(gBh + tb + lsrc + 1024, sBh + soff + 1024);
    gload_lds16(gAl + tb + lsrc,        sAl + soff);
    gload_lds16(gAl + tb + lsrc + 1024, sAl + soff + 1024);
    gload_lds16(gBl + tb + lsrc,        sBl + soff);
    gload_lds16(gBl + tb + lsrc + 1024, sBl + soff + 1024);
    __syncthreads();
    f16x8 a_h[4], b_h[4], a_l[4], b_l[4];
    #pragma unroll
    for (int m = 0; m < 4; ++m) { a_h[m] = *(const f16x8*)(sAh + aoff + m*1024);
                                  a_l[m] = *(const f16x8*)(sAl + aoff + m*1024); }
    #pragma unroll
    for (int n = 0; n < 4; ++n) { b_h[n] = *(const f16x8*)(sBh + boff + n*1024);
                                  b_l[n] = *(const f16x8*)(sBl + boff + n*1024); }
    #pragma unroll
    for (int m = 0; m < 4; ++m)
      #pragma unroll
      for (int n = 0; n < 4; ++n) {
        acc[m][n] = __builtin_amdgcn_mfma_f32_16x16x32_f16(a_h[m], b_h[n], acc[m][n], 0, 0, 0);
        acc[m][n] = __builtin_amdgcn_mfma_f32_16x16x32_f16(a_l[m], b_h[n], acc[m][n], 0, 0, 0);
        acc[m][n] = __builtin_amdgcn_mfma_f32_16x16x32_f16(a_h[m], b_l[n], acc[m][n], 0, 0, 0);
      }
    __syncthreads();
  }
  #pragma unroll
  for (int m = 0; m < 4; ++m)
    #pragma unroll
    for (int n = 0; n < 4; ++n) {
      int col = bx*128 + wc*64 + n*16 + (lane&15);
      float bv = bias[col];
      #pragma unroll
      for (int rr = 0; rr < 4; ++rr) {
        int row = by*128 + wr*64 + m*16 + (lane>>4)*4 + rr;
        out[(size_t)row*1024 + col] = acc[m][n][rr] + bv;
      }
    }
}

// ---------------- per-row attention -> writes WH/WL fragment tiles directly ----------------
__global__ __launch_bounds__(256) void k_attn(const float* __restrict__ OVL,
                                              const float* __restrict__ HID,
                                              const float* __restrict__ n2,
                                              const float* __restrict__ VG,
                                              const float* __restrict__ pb1,
                                              const float* __restrict__ pw2,
                                              const float* __restrict__ pb2,
                                              const float* __restrict__ gb,
                                              _Float16* __restrict__ WH,
                                              _Float16* __restrict__ WL) {
  int r = blockIdx.x;
  int tid = threadIdx.x;
  __shared__ float sov[512];
  __shared__ float shid[128];
  __shared__ float sp[8], srsum[8], sred[4][8], slog[8], sgate[8];
  for (int i = tid; i < 512; i += 256) sov[i] = OVL[(size_t)r*512 + i];
  if (tid < 128) shid[tid] = HID[(size_t)r*128 + tid];
  __syncthreads();
  if (tid < 8) {
    int hh = tid;
    float z = pb2[hh];
    #pragma unroll
    for (int kk = 0; kk < 16; ++kk) {
      float x = shid[hh*16 + kk] + pb1[hh*16 + kk];
      float sg = 1.f / (1.f + expf(-x));
      z += x * sg * pw2[hh*16 + kk];
    }
    sp[hh] = 0.95f / (1.f + expf(-z));
  }
  __syncthreads();
  int hh = tid >> 5, j = tid & 31;
  float p = sp[hh];
  float inv_n2 = 1.f / fmaxf(n2[(size_t)r * 8 + hh], 1e-24f);
  float base = (1.f - p) * 0.0078125f;
  float r0 = p * (sov[hh*64 + j]      * inv_n2) + base;
  float r1 = p * (sov[hh*64 + j + 32] * inv_n2) + base;
  float partial = r0 + r1;
  #pragma unroll
  for (int off = 1; off < 32; off <<= 1) partial += __shfl_xor(partial, off);
  if (j == 0) srsum[hh] = partial;
  __syncthreads();
  float inv_den = 1.f / (srsum[hh] + 1e-8f);
  float a0 = r0 * inv_den, a1 = r1 * inv_den;
  float lg[8];
  {
    const float* v0 = VG + (size_t)(hh*64 + j) * 8;
    const float* v1 = VG + (size_t)(hh*64 + j + 32) * 8;
    #pragma unroll
    for (int g = 0; g < 8; ++g) lg[g] = a0 * v0[g] + a1 * v1[g];
  }
  #pragma unroll
  for (int off = 1; off < 64; off <<= 1)
    #pragma unroll
    for (int g = 0; g < 8; ++g) lg[g] += __shfl_xor(lg[g], off);
  if ((tid & 63) == 0) {
    int w = tid >> 6;
    #pragma unroll
    for (int g = 0; g < 8; ++g) sred[w][g] = lg[g];
  }
  __syncthreads();
  if (tid < 8)
    slog[tid] = sred[0][tid] + sred[1][tid] + sred[2][tid] + sred[3][tid] + gb[tid];
  __syncthreads();
  if (tid < 8) {
    float mx = slog[0];
    #pragma unroll
    for (int g = 1; g < 8; ++g) mx = fmaxf(mx, slog[g]);
    float den = 0.f;
    #pragma unroll
    for (int g = 0; g < 8; ++g) den += expf(slog[g] - mx);
    sgate[tid] = expf(slog[tid] - mx) / den;
  }
  __syncthreads();
  float gte = sgate[hh];
  float wa0 = a0 * gte, wa1 = a1 * gte;
  int mt = r >> 7, r8 = (r >> 4) & 7, r15 = r & 15;
  int kg = (j >> 3) & 3, jj = j & 7;
  size_t sub = (size_t)r8*512 + kg*128 + r15*8 + jj;
  size_t b0 = ((size_t)mt*16 + hh*2)     * 4096 + sub;
  size_t b1 = ((size_t)mt*16 + hh*2 + 1) * 4096 + sub;
  _Float16 h0, l0, h1, l1;
  split16(wa0, h0, l0);
  split16(wa1, h1, l1);
  WH[b0] = h0; WL[b0] = l0;
  WH[b1] = h1; WL[b1] = l1;
}

extern "C" void kernel_launch(void* const* d_in, const int* in_sizes, int n_in,
                              void* d_out, int out_size, void* d_ws, size_t ws_size,
                              hipStream_t stream) {
  const float* h_   = (const float*)d_in[0];
  const float* Wr   = (const float*)d_in[1];
  const float* Wi   = (const float*)d_in[2];
  const float* pw1  = (const float*)d_in[3];
  const float* pb1  = (const float*)d_in[4];
  const float* pw2  = (const float*)d_in[5];
  const float* pb2  = (const float*)d_in[6];
  const float* mr   = (const float*)d_in[7];
  const float* mi   = (const float*)d_in[8];
  const float* vals = (const float*)d_in[9];
  const float* gw   = (const float*)d_in[10];
  const float* gb   = (const float*)d_in[11];
  const float* ow   = (const float*)d_in[12];
  const float* ob   = (const float*)d_in[13];

  if (ws_size < WS_FLOATS * sizeof(float)) return;

  float* ws   = (float*)d_ws;
  float* OVL  = ws + OFF_OVL;
  float* HID  = ws + OFF_HID;
  float* n2   = ws + OFF_N2;
  float* VG   = ws + OFF_VG;
  float* mReN = ws + OFF_MRE;
  float* mImN = ws + OFF_MIM;
  float* VW   = ws + OFF_AH;           // fp32 VW scratch; dead before convA writes AH
  _Float16* VWH = (_Float16*)(ws + OFF_VWH);
  _Float16* VWL = (_Float16*)(ws + OFF_VWL);
  _Float16* BH  = (_Float16*)(ws + OFF_BH);
  _Float16* BL  = (_Float16*)(ws + OFF_BL);
  _Float16* AH  = (_Float16*)(ws + OFF_AH);
  _Float16* AL  = (_Float16*)(ws + OFF_AL);
  _Float16* WH  = (_Float16*)(ws + OFF_AH);  // alias: A dead after k_qval
  _Float16* WL  = (_Float16*)(ws + OFF_AL);

  hipMemsetAsync(n2, 0, (size_t)ROWS * 8 * sizeof(float), stream);
  k_prep_mem<<<512, 64, 0, stream>>>(mr, mi, mReN, mImN);
  k_prep_vg<<<512, 256, 0, stream>>>(vals, gw, VG);
  k_prep_b16<<<1088, 256, 0, stream>>>(Wr, Wi, pw1, BH, BL);
  k_prep_aov16<<<256, 256, 0, stream>>>(Wr, Wi, mReN, mImN, BH, BL);
  k_gemm64<<<dim3(16, 8), 256, 0, stream>>>(vals, ow, VW, 1024, 1024, 1024, 1024);
  k_convB<<<128, 256, 0, stream>>>(VW, 1024, 16, VWH, VWL);
  k_convA<<<4096, 256, 0, stream>>>(h_, AH, AL);
  k_qnorm<<<2048, 256, 0, stream>>>(AH, BH, n2);
  k_qval<<<1152, 256, 0, stream>>>(AH, AL, BH, BL, OVL, HID);
  k_attn<<<ROWS, 256, 0, stream>>>(OVL, HID, n2, VG, pb1, pw2, pb2, gb, WH, WL);
  k_fin<<<dim3(8, 128), 256, 0, stream>>>(WH, WL, VWH, VWL, ob, (float*)d_out);
}

// Round 9
// 479.210 us; speedup vs baseline: 1.0619x; 1.0619x over previous
//
#include <hip/hip_runtime.h>
#include <hip/hip_bf16.h>
#include <math.h>

#define ROWS 16384   // B*N = 8*2048

typedef _Float16 f16x8 __attribute__((ext_vector_type(8)));
typedef float f32x4 __attribute__((ext_vector_type(4)));

// ---- workspace offsets (floats); total identical to proven 31,330,304 ----
static const size_t OFF_OVL = 0;            // 16384*512 fp32 overlap
static const size_t OFF_HID = 8388608;      // 16384*128 fp32
static const size_t OFF_N2  = 10485760;     // 16384*8  (n2a)
static const size_t OFF_VG  = 10616832;     // 512*8
static const size_t OFF_MRE = 10620928;     // 65536 (mReN; later n2b low half)
static const size_t OFF_MIM = 10686464;     // 65536 (mImN; later n2b high half)
static const size_t OFF_VWH = 10752000;     // 512*1024 f16 = 262144 fl
static const size_t OFF_VWL = 11014144;     // 262144 fl
static const size_t OFF_BH  = 11276288;     // 1024*3200 f16 = 1638400 fl
static const size_t OFF_BL  = 12914688;     // 1638400 fl
static const size_t OFF_AH  = 14553088;     // 16384*1024 f16 = 8388608 fl; late: WH alias
static const size_t OFF_AL  = 22941696;     // 8388608 fl; late: WL alias
static const size_t WS_FLOATS = 31330304;   // 125.32 MB

__device__ __forceinline__ void gload_lds16(const void* g, void* l) {
  __builtin_amdgcn_global_load_lds((const __attribute__((address_space(1))) void*)g,
                                   (__attribute__((address_space(3))) void*)l, 16, 0, 0);
}

__device__ __forceinline__ void split16(float v, _Float16& hi, _Float16& lo) {
  _Float16 h = (_Float16)v;
  hi = h;
  lo = (_Float16)(v - (float)h);
}

// ---------------- prep: normalize memory states ----------------
__global__ void k_prep_mem(const float* __restrict__ mr, const float* __restrict__ mi,
                           float* __restrict__ mReN, float* __restrict__ mImN) {
  int hs = blockIdx.x;
  int t  = threadIdx.x;
  const float* pr = mr + (size_t)hs * 128;
  const float* pi = mi + (size_t)hs * 128;
  float a0 = pr[t], a1 = pr[t + 64], b0 = pi[t], b1 = pi[t + 64];
  float ss = a0*a0 + a1*a1 + b0*b0 + b1*b1;
  #pragma unroll
  for (int off = 1; off < 64; off <<= 1) ss += __shfl_xor(ss, off);
  float inv = 1.f / fmaxf(sqrtf(ss), 1e-12f);
  mReN[(size_t)hs*128 + t]      = a0 * inv;
  mReN[(size_t)hs*128 + t + 64] = a1 * inv;
  mImN[(size_t)hs*128 + t]      = b0 * inv;
  mImN[(size_t)hs*128 + t + 64] = b1 * inv;
}

// ---------------- prep: VG[h,s,g] ----------------
__global__ __launch_bounds__(256) void k_prep_vg(const float* __restrict__ vals,
                                                 const float* __restrict__ gw,
                                                 float* __restrict__ VG) {
  int hs = blockIdx.x;
  int h  = hs >> 6;
  int t  = threadIdx.x;
  float acc[8] = {0,0,0,0,0,0,0,0};
  for (int dd = t; dd < 1024; dd += 256) {
    float v = vals[(size_t)hs*1024 + dd];
    const float* g = gw + (size_t)(h*1024 + dd)*8;
    #pragma unroll
    for (int q = 0; q < 8; ++q) acc[q] += v * g[q];
  }
  #pragma unroll
  for (int off = 1; off < 64; off <<= 1)
    #pragma unroll
    for (int q = 0; q < 8; ++q) acc[q] += __shfl_xor(acc[q], off);
  __shared__ float red[4][8];
  if ((t & 63) == 0) {
    #pragma unroll
    for (int q = 0; q < 8; ++q) red[t >> 6][q] = acc[q];
  }
  __syncthreads();
  if (t < 8) VG[(size_t)hs*8 + t] = red[0][t] + red[1][t] + red[2][t] + red[3][t];
}

// ---------------- prep: Wr/Wi/pw1 -> BH/BL fragment tiles directly ----------------
__global__ __launch_bounds__(256) void k_prep_b16(const float* __restrict__ Wr,
                                                  const float* __restrict__ Wi,
                                                  const float* __restrict__ pw1,
                                                  _Float16* __restrict__ BH,
                                                  _Float16* __restrict__ BL) {
  int g = blockIdx.x * 256 + threadIdx.x;   // 128*2176 = 278528 total
  int c  = g % 2176;
  int k0 = g / 2176;                        // 0..127 (8 consecutive k)
  float v[8];
  if (c < 1024) {
    int h = c >> 7, e = c & 127;
    const float* p = Wr + ((size_t)(h << 10) + k0*8) * 128 + e;
    #pragma unroll
    for (int j = 0; j < 8; ++j) v[j] = p[(size_t)j*128];
  } else if (c < 2048) {
    int c2 = c - 1024; int h = c2 >> 7, e = c2 & 127;
    const float* p = Wi + ((size_t)(h << 10) + k0*8) * 128 + e;
    #pragma unroll
    for (int j = 0; j < 8; ++j) v[j] = p[(size_t)j*128];
  } else {
    int q = c - 2048; int h = q >> 4, kk = q & 15;
    const float* p = pw1 + ((size_t)(h << 10) + k0*8) * 16 + kk;
    #pragma unroll
    for (int j = 0; j < 8; ++j) v[j] = p[(size_t)j*16];
  }
  int Bcol = (c < 2048) ? c : 3072 + (c - 2048);
  int nt = Bcol >> 7, c8 = (Bcol >> 4) & 7, c15 = Bcol & 15;
  int kt = k0 >> 2, kg = k0 & 3;
  size_t base = ((size_t)nt*32 + kt)*4096 + c8*512 + kg*128 + c15*8;
  f16x8 hv, lv;
  #pragma unroll
  for (int j = 0; j < 8; ++j) { _Float16 hi, lo; split16(v[j], hi, lo); hv[j] = hi; lv[j] = lo; }
  *(f16x8*)(BH + base) = hv;
  *(f16x8*)(BL + base) = lv;
}

// ---------------- prep: Aov -> BH/BL fragment tiles (nt 16..23) ----------------
__global__ __launch_bounds__(256) void k_prep_aov16(const float* __restrict__ Wr,
                                                    const float* __restrict__ Wi,
                                                    const float* __restrict__ mReN,
                                                    const float* __restrict__ mImN,
                                                    _Float16* __restrict__ BH,
                                                    _Float16* __restrict__ BL) {
  int bid = blockIdx.x;          // h(8) x kt64(16) x shalf(2)
  int h   = bid >> 5;
  int kt64 = (bid >> 1) & 15;
  int sh  = bid & 1;
  __shared__ float sRe[32][129];
  __shared__ float sIm[32][129];
  int tid = threadIdx.x;
  int s0 = sh * 32;
  for (int i = tid; i < 32 * 32; i += 256) {
    int s = i >> 5; int e4 = (i & 31) << 2;
    *(float4*)&sRe[s][e4] = *(const float4*)(mReN + ((size_t)(h*64 + s0 + s)*128 + e4));
    *(float4*)&sIm[s][e4] = *(const float4*)(mImN + ((size_t)(h*64 + s0 + s)*128 + e4));
  }
  __syncthreads();
  int kq = tid >> 5;
  int s  = tid & 31;
  int kbase = kt64*64 + kq*8;
  float aR[8] = {0,0,0,0,0,0,0,0}, aI[8] = {0,0,0,0,0,0,0,0};
  for (int e0 = 0; e0 < 128; e0 += 4) {
    float4 mre = *(float4*)&sRe[s][e0];
    float4 mim = *(float4*)&sIm[s][e0];
    #pragma unroll
    for (int j = 0; j < 8; ++j) {
      const float4 wr = *(const float4*)(Wr + ((size_t)(h*1024 + kbase + j))*128 + e0);
      const float4 wi = *(const float4*)(Wi + ((size_t)(h*1024 + kbase + j))*128 + e0);
      aR[j] += wr.x*mre.x + wr.y*mre.y + wr.z*mre.z + wr.w*mre.w
             + wi.x*mim.x + wi.y*mim.y + wi.z*mim.z + wi.w*mim.w;
      aI[j] += wi.x*mre.x + wi.y*mre.y + wi.z*mre.z + wi.w*mre.w
             - (wr.x*mim.x + wr.y*mim.y + wr.z*mim.z + wr.w*mim.w);
    }
  }
  int kt32 = kbase >> 5;
  int kg   = (kbase >> 3) & 3;
  int coln = s0 + s;
  size_t baseR = ((size_t)(16 + h)*32 + kt32)*4096 + (size_t)(coln >> 4)*512 + kg*128 + (coln & 15)*8;
  size_t baseI = baseR + 4*512;
  f16x8 hR, lR, hI, lI;
  #pragma unroll
  for (int j = 0; j < 8; ++j) {
    _Float16 hi, lo;
    split16(aR[j], hi, lo); hR[j] = hi; lR[j] = lo;
    split16(aI[j], hi, lo); hI[j] = hi; lI[j] = lo;
  }
  *(f16x8*)(BH + baseR) = hR; *(f16x8*)(BL + baseR) = lR;
  *(f16x8*)(BH + baseI) = hI; *(f16x8*)(BL + baseI) = lI;
}

// ---------------- VW = values_flat(512x1024) @ out_w(1024x1024) -> VWH/VWL fragment tiles ----------------
__global__ __launch_bounds__(256) void k_gemm64(const float* __restrict__ A,
                                                const float* __restrict__ B,
                                                int K, int lda, int ldb,
                                                _Float16* __restrict__ dh,
                                                _Float16* __restrict__ dl) {
  __shared__ float As[16][64];
  __shared__ float Bs[16][64];
  int tid = threadIdx.x;
  int tm = tid >> 4, tn = tid & 15;
  float acc[4][4];
  #pragma unroll
  for (int i = 0; i < 4; ++i)
    #pragma unroll
    for (int j = 0; j < 4; ++j) acc[i][j] = 0.f;
  int row0 = blockIdx.y << 6, col0 = blockIdx.x << 6;
  int ar = tid >> 2, ak = (tid & 3) << 2;
  int bkr = tid >> 4, bc = (tid & 15) << 2;
  for (int kt = 0; kt < K; kt += 16) {
    float4 a0 = *(const float4*)(A + (size_t)(row0 + ar)*lda + kt + ak);
    float4 b0 = *(const float4*)(B + (size_t)(kt + bkr)*ldb + col0 + bc);
    __syncthreads();
    As[ak+0][ar] = a0.x; As[ak+1][ar] = a0.y; As[ak+2][ar] = a0.z; As[ak+3][ar] = a0.w;
    *(float4*)&Bs[bkr][bc] = b0;
    __syncthreads();
    #pragma unroll
    for (int k = 0; k < 16; ++k) {
      float af[4], bf[4];
      *(float4*)&af[0] = *(const float4*)&As[k][tm << 2];
      *(float4*)&bf[0] = *(const float4*)&Bs[k][tn << 2];
      #pragma unroll
      for (int i = 0; i < 4; ++i)
        #pragma unroll
        for (int j = 0; j < 4; ++j) acc[i][j] += af[i] * bf[j];
    }
  }
  // write B-side fragment tiles directly (k-dim 512 -> 16 k-tiles for k_fin)
  #pragma unroll
  for (int i = 0; i < 4; ++i) {
    int row = row0 + (tm << 2) + i;            // k-dim 0..511
    int ktl = row >> 5, kg = (row >> 3) & 3, jj = row & 7;
    #pragma unroll
    for (int j = 0; j < 4; ++j) {
      int col = col0 + (tn << 2) + j;          // 0..1023
      int nt = col >> 7, c8 = (col >> 4) & 7, c15 = col & 15;
      size_t base = ((size_t)nt*16 + ktl)*4096 + c8*512 + kg*128 + c15*8 + jj;
      _Float16 hi, lo; split16(acc[i][j], hi, lo);
      dh[base] = hi; dl[base] = lo;
    }
  }
}

// ---------------- convA: row-major fp32 -> hi/lo f16 fragment tiles (round-4 proven) ----------------
__global__ __launch_bounds__(256) void k_convA(const float* __restrict__ src, int lda, int ktiles,
                                               _Float16* __restrict__ dh, _Float16* __restrict__ dl) {
  int mt = blockIdx.x / ktiles, kt = blockIdx.x % ktiles;
  size_t base = (size_t)blockIdx.x * 4096;
  for (int q = 0; q < 16; ++q) {
    int i = q*256 + threadIdx.x;
    int r8 = i >> 9, kg = (i >> 7) & 3, r15 = (i >> 3) & 15, j = i & 7;
    int row = mt*128 + r8*16 + r15;
    int k   = kt*32 + kg*8 + j;
    float v = src[(size_t)row*lda + k];
    _Float16 hi, lo; split16(v, hi, lo);
    dh[base + i] = hi; dl[base + i] = lo;
  }
}

// ---------------- norm GEMM: hi-only, 128x128, double-buffered; n2a (XR) / n2b (XI), LDS wc-combine ----------------
__global__ __launch_bounds__(256) void k_qnorm(const _Float16* __restrict__ Ah,
                                               const _Float16* __restrict__ Bh,
                                               float* __restrict__ n2a,
                                               float* __restrict__ n2b) {
  __shared__ __align__(16) char smem[32768];
  const int id = blockIdx.x;
  const int by = (id & 7) * 16 + ((id >> 3) & 15);
  const int bx = id >> 7;                      // 0..15
  const int tid = threadIdx.x;
  const int wid = tid >> 6, lane = tid & 63;
  const int wr = wid >> 1, wc = wid & 1;
  const char* gA = (const char*)Ah + (size_t)by * 32 * 8192;
  const char* gB = (const char*)Bh + (size_t)bx * 32 * 8192;

  f32x4 acc[4][4];
  #pragma unroll
  for (int i = 0; i < 4; ++i)
    #pragma unroll
    for (int j = 0; j < 4; ++j) acc[i][j] = (f32x4){0.f,0.f,0.f,0.f};

  auto stage = [&](int b, int kt) {
    const char* srcA = gA + (size_t)kt * 8192;
    const char* srcB = gB + (size_t)kt * 8192;
    char* dA = smem + b * 8192;
    char* dB = smem + 16384 + b * 8192;
    #pragma unroll
    for (int q = 0; q < 4; ++q) {
      int c = wid * 4 + q;
      int sub = (c & 7) * 1024;
      if (c < 8) gload_lds16(srcA + sub + lane*16, dA + sub);
      else       gload_lds16(srcB + sub + lane*16, dB + sub);
    }
  };

  stage(0, 0);
  asm volatile("s_waitcnt vmcnt(0)" ::: "memory");
  __builtin_amdgcn_s_barrier();
  int cur = 0;
  for (int kt = 0; kt < 32; ++kt) {
    if (kt < 31) stage(cur ^ 1, kt + 1);
    const char* cA = smem + cur * 8192;
    const char* cB = smem + 16384 + cur * 8192;
    f16x8 a[4], b[4];
    #pragma unroll
    for (int m = 0; m < 4; ++m) a[m] = *(const f16x8*)(cA + wr*4096 + m*1024 + lane*16);
    #pragma unroll
    for (int n = 0; n < 4; ++n) b[n] = *(const f16x8*)(cB + wc*4096 + n*1024 + lane*16);
    #pragma unroll
    for (int m = 0; m < 4; ++m)
      #pragma unroll
      for (int n = 0; n < 4; ++n)
        acc[m][n] = __builtin_amdgcn_mfma_f32_16x16x32_f16(a[m], b[n], acc[m][n], 0, 0, 0);
    if (kt < 31) {
      asm volatile("s_waitcnt vmcnt(0)" ::: "memory");
      __builtin_amdgcn_s_barrier();
    }
    cur ^= 1;
  }

  // per-row partial (64 cols per wc wave), then combine across wc via LDS
  float rsv[16];
  #pragma unroll
  for (int m = 0; m < 4; ++m)
    #pragma unroll
    for (int rr = 0; rr < 4; ++rr) {
      float rs = 0.f;
      #pragma unroll
      for (int n = 0; n < 4; ++n) rs += acc[m][n][rr] * acc[m][n][rr];
      rs += __shfl_xor(rs, 1); rs += __shfl_xor(rs, 2);
      rs += __shfl_xor(rs, 4); rs += __shfl_xor(rs, 8);
      rsv[m*4 + rr] = rs;
    }
  __syncthreads();                 // LDS staging buffers now dead
  float* scomb = (float*)smem;     // [128] per-row partial from wc=0
  if (wc == 0) {
    #pragma unroll
    for (int m = 0; m < 4; ++m)
      #pragma unroll
      for (int rr = 0; rr < 4; ++rr)
        if ((lane & 15) == 0)
          scomb[wr*64 + m*16 + (lane >> 4)*4 + rr] = rsv[m*4 + rr];
  }
  __syncthreads();
  if (wc == 1) {
    const int head = bx & 7;
    float* dst = (bx < 8) ? n2a : n2b;
    #pragma unroll
    for (int m = 0; m < 4; ++m)
      #pragma unroll
      for (int rr = 0; rr < 4; ++rr)
        if ((lane & 15) == 0) {
          int r128 = wr*64 + m*16 + (lane >> 4)*4 + rr;
          dst[(size_t)(by*128 + r128)*8 + head] = rsv[m*4 + rr] + scomb[r128];
        }
  }
}

// ---------------- value GEMM: 3-term, 128x128, double-buffered (bx<8: OV head, bx==8: HID) ----------------
__global__ __launch_bounds__(256) void k_qval(const _Float16* __restrict__ Ah,
                                              const _Float16* __restrict__ Al,
                                              const _Float16* __restrict__ Bh,
                                              const _Float16* __restrict__ Bl,
                                              float* __restrict__ OVL,
                                              float* __restrict__ HID) {
  __shared__ __align__(16) char smem[65536];   // 2 bufs x {Ah,Al,Bh,Bl} x 8KB
  const int id = blockIdx.x;
  const int rest = id >> 3;
  const int by = (id & 7) * 16 + (rest & 15);
  const int bx = rest >> 4;                    // 0..8
  const int tid = threadIdx.x;
  const int wid = tid >> 6, lane = tid & 63;
  const int wr = wid >> 1, wc = wid & 1;
  f32x4 acc[4][4];
  #pragma unroll
  for (int i = 0; i < 4; ++i)
    #pragma unroll
    for (int j = 0; j < 4; ++j) acc[i][j] = (f32x4){0.f,0.f,0.f,0.f};

  const char* pAh = (const char*)Ah + (size_t)by*32*8192;
  const char* pAl = (const char*)Al + (size_t)by*32*8192;
  const char* pBh = (const char*)Bh + (size_t)(16 + bx)*32*8192;
  const char* pBl = (const char*)Bl + (size_t)(16 + bx)*32*8192;
  const char* mysrc = (wid == 0) ? pAh : (wid == 1) ? pAl : (wid == 2) ? pBh : pBl;

  auto stage = [&](int b, int kt) {
    const char* s = mysrc + (size_t)kt*8192 + lane*16;
    char* d = smem + b*32768 + wid*8192;
    #pragma unroll
    for (int q = 0; q < 8; ++q)
      gload_lds16(s + q*1024, d + q*1024);
  };

  stage(0, 0);
  asm volatile("s_waitcnt vmcnt(0)" ::: "memory");
  __builtin_amdgcn_s_barrier();
  int cur = 0;
  for (int kt = 0; kt < 32; ++kt) {
    if (kt < 31) stage(cur ^ 1, kt + 1);
    const char* base = smem + cur*32768;
    const char* cAh = base;
    const char* cAl = base + 8192;
    const char* cBh = base + 16384;
    const char* cBl = base + 24576;
    f16x8 a_h[4], a_l[4], b_h[4], b_l[4];
    #pragma unroll
    for (int m = 0; m < 4; ++m) { a_h[m] = *(const f16x8*)(cAh + wr*4096 + m*1024 + lane*16);
                                  a_l[m] = *(const f16x8*)(cAl + wr*4096 + m*1024 + lane*16); }
    #pragma unroll
    for (int n = 0; n < 4; ++n) { b_h[n] = *(const f16x8*)(cBh + wc*4096 + n*1024 + lane*16);
                                  b_l[n] = *(const f16x8*)(cBl + wc*4096 + n*1024 + lane*16); }
    #pragma unroll
    for (int m = 0; m < 4; ++m)
      #pragma unroll
      for (int n = 0; n < 4; ++n) {
        acc[m][n] = __builtin_amdgcn_mfma_f32_16x16x32_f16(a_h[m], b_h[n], acc[m][n], 0, 0, 0);
        acc[m][n] = __builtin_amdgcn_mfma_f32_16x16x32_f16(a_l[m], b_h[n], acc[m][n], 0, 0, 0);
        acc[m][n] = __builtin_amdgcn_mfma_f32_16x16x32_f16(a_h[m], b_l[n], acc[m][n], 0, 0, 0);
      }
    if (kt < 31) {
      asm volatile("s_waitcnt vmcnt(0)" ::: "memory");
      __builtin_amdgcn_s_barrier();
    }
    cur ^= 1;
  }
  __syncthreads();   // all waves done with LDS buffers before epilogue reuse

  if (bx == 8) {
    #pragma unroll
    for (int m = 0; m < 4; ++m)
      #pragma unroll
      for (int n = 0; n < 4; ++n)
        #pragma unroll
        for (int rr = 0; rr < 4; ++rr) {
          int row = by*128 + wr*64 + m*16 + (lane>>4)*4 + rr;
          int col = wc*64 + n*16 + (lane&15);
          HID[(size_t)row*128 + col] = acc[m][n][rr];
        }
  } else {
    float* sOv = (float*)smem;   // [128][68]
    if (wc == 0) {
      #pragma unroll
      for (int m = 0; m < 4; ++m)
        #pragma unroll
        for (int n = 0; n < 4; ++n)
          #pragma unroll
          for (int rr = 0; rr < 4; ++rr) {
            int r128 = wr*64 + m*16 + (lane>>4)*4 + rr;
            int s = n*16 + (lane&15);
            sOv[r128*68 + s] = acc[m][n][rr]*acc[m][n][rr];
          }
    }
    __syncthreads();
    if (wc == 1) {
      #pragma unroll
      for (int m = 0; m < 4; ++m)
        #pragma unroll
        for (int n = 0; n < 4; ++n)
          #pragma unroll
          for (int rr = 0; rr < 4; ++rr) {
            int r128 = wr*64 + m*16 + (lane>>4)*4 + rr;
            int s = n*16 + (lane&15);
            float v = sOv[r128*68 + s] + acc[m][n][rr]*acc[m][n][rr];
            int row = by*128 + r128;
            OVL[(size_t)row*512 + bx*64 + s] = v;
          }
    }
  }
}

// ---------------- final MFMA GEMM: out = wattn(16384x512) @ VW(512x1024) + out_b ----------------
__global__ __launch_bounds__(256) void k_fin(const _Float16* __restrict__ Ahh,
                                             const _Float16* __restrict__ Alo,
                                             const _Float16* __restrict__ Bhh,
                                             const _Float16* __restrict__ Blo,
                                             const float* __restrict__ bias,
                                             float* __restrict__ out) {
  __shared__ __align__(16) char smem[32768];
  const int bx = blockIdx.x;   // 0..7
  const int by = blockIdx.y;   // 0..127
  const int tid = threadIdx.x;
  const int wid = tid >> 6, lane = tid & 63;
  const int wr = wid >> 1, wc = wid & 1;
  char* sAh = smem;
  char* sAl = smem + 8192;
  char* sBh = smem + 16384;
  char* sBl = smem + 24576;
  f32x4 acc[4][4];
  #pragma unroll
  for (int i = 0; i < 4; ++i)
    #pragma unroll
    for (int j = 0; j < 4; ++j) acc[i][j] = (f32x4){0.f,0.f,0.f,0.f};
  const char* gAh = (const char*)Ahh + (size_t)by*16*8192;
  const char* gAl = (const char*)Alo + (size_t)by*16*8192;
  const char* gBh = (const char*)Bhh + (size_t)bx*16*8192;
  const char* gBl = (const char*)Blo + (size_t)bx*16*8192;
  const int soff = wid*2048;
  const int lsrc = soff + lane*16;
  const int aoff = wr*4096 + lane*16;
  const int boff = wc*4096 + lane*16;
  for (int kt = 0; kt < 16; ++kt) {
    const size_t tb = (size_t)kt*8192;
    gload_lds16(gAh + tb + lsrc,        sAh + soff);
    gload_lds16(gAh + tb + lsrc + 1024, sAh + soff + 1024);
    gload_lds16(gBh + tb + lsrc,        sBh + soff);
    gload_lds16(gBh + tb + lsrc + 1024, sBh + soff + 1024);
    gload_lds16(gAl + tb + lsrc,        sAl + soff);
    gload_lds16(gAl + tb + lsrc + 1024, sAl + soff + 1024);
    gload_lds16(gBl + tb + lsrc,        sBl + soff);
    gload_lds16(gBl + tb + lsrc + 1024, sBl + soff + 1024);
    __syncthreads();
    f16x8 a_h[4], b_h[4], a_l[4], b_l[4];
    #pragma unroll
    for (int m = 0; m < 4; ++m) { a_h[m] = *(const f16x8*)(sAh + aoff + m*1024);
                                  a_l[m] = *(const f16x8*)(sAl + aoff + m*1024); }
    #pragma unroll
    for (int n = 0; n < 4; ++n) { b_h[n] = *(const f16x8*)(sBh + boff + n*1024);
                                  b_l[n] = *(const f16x8*)(sBl + boff + n*1024); }
    #pragma unroll
    for (int m = 0; m < 4; ++m)
      #pragma unroll
      for (int n = 0; n < 4; ++n) {
        acc[m][n] = __builtin_amdgcn_mfma_f32_16x16x32_f16(a_h[m], b_h[n], acc[m][n], 0, 0, 0);
        acc[m][n] = __builtin_amdgcn_mfma_f32_16x16x32_f16(a_l[m], b_h[n], acc[m][n], 0, 0, 0);
        acc[m][n] = __builtin_amdgcn_mfma_f32_16x16x32_f16(a_h[m], b_l[n], acc[m][n], 0, 0, 0);
      }
    __syncthreads();
  }
  #pragma unroll
  for (int m = 0; m < 4; ++m)
    #pragma unroll
    for (int n = 0; n < 4; ++n) {
      int col = bx*128 + wc*64 + n*16 + (lane&15);
      float bv = bias[col];
      #pragma unroll
      for (int rr = 0; rr < 4; ++rr) {
        int row = by*128 + wr*64 + m*16 + (lane>>4)*4 + rr;
        out[(size_t)row*1024 + col] = acc[m][n][rr] + bv;
      }
    }
}

// ---------------- per-row attention -> writes WH/WL fragment tiles directly ----------------
__global__ __launch_bounds__(256) void k_attn(const float* __restrict__ OVL,
                                              const float* __restrict__ HID,
                                              const float* __restrict__ n2a,
                                              const float* __restrict__ n2b,
                                              const float* __restrict__ VG,
                                              const float* __restrict__ pb1,
                                              const float* __restrict__ pw2,
                                              const float* __restrict__ pb2,
                                              const float* __restrict__ gb,
                                              _Float16* __restrict__ WH,
                                              _Float16* __restrict__ WL) {
  int r = blockIdx.x;
  int tid = threadIdx.x;
  __shared__ float sov[512];
  __shared__ float shid[128];
  __shared__ float sp[8], srsum[8], sred[4][8], slog[8], sgate[8];
  for (int i = tid; i < 512; i += 256) sov[i] = OVL[(size_t)r*512 + i];
  if (tid < 128) shid[tid] = HID[(size_t)r*128 + tid];
  __syncthreads();
  if (tid < 8) {
    int hh = tid;
    float z = pb2[hh];
    #pragma unroll
    for (int kk = 0; kk < 16; ++kk) {
      float x = shid[hh*16 + kk] + pb1[hh*16 + kk];
      float sg = 1.f / (1.f + expf(-x));
      z += x * sg * pw2[hh*16 + kk];
    }
    sp[hh] = 0.95f / (1.f + expf(-z));
  }
  __syncthreads();
  int hh = tid >> 5, j = tid & 31;
  float p = sp[hh];
  float nn = n2a[(size_t)r * 8 + hh] + n2b[(size_t)r * 8 + hh];
  float inv_n2 = 1.f / fmaxf(nn, 1e-24f);
  float base = (1.f - p) * 0.0078125f;
  float r0 = p * (sov[hh*64 + j]      * inv_n2) + base;
  float r1 = p * (sov[hh*64 + j + 32] * inv_n2) + base;
  float partial = r0 + r1;
  #pragma unroll
  for (int off = 1; off < 32; off <<= 1) partial += __shfl_xor(partial, off);
  if (j == 0) srsum[hh] = partial;
  __syncthreads();
  float inv_den = 1.f / (srsum[hh] + 1e-8f);
  float a0 = r0 * inv_den, a1 = r1 * inv_den;
  float lg[8];
  {
    const float* v0 = VG + (size_t)(hh*64 + j) * 8;
    const float* v1 = VG + (size_t)(hh*64 + j + 32) * 8;
    #pragma unroll
    for (int g = 0; g < 8; ++g) lg[g] = a0 * v0[g] + a1 * v1[g];
  }
  #pragma unroll
  for (int off = 1; off < 64; off <<= 1)
    #pragma unroll
    for (int g = 0; g < 8; ++g) lg[g] += __shfl_xor(lg[g], off);
  if ((tid & 63) == 0) {
    int w = tid >> 6;
    #pragma unroll
    for (int g = 0; g < 8; ++g) sred[w][g] = lg[g];
  }
  __syncthreads();
  if (tid < 8)
    slog[tid] = sred[0][tid] + sred[1][tid] + sred[2][tid] + sred[3][tid] + gb[tid];
  __syncthreads();
  if (tid < 8) {
    float mx = slog[0];
    #pragma unroll
    for (int g = 1; g < 8; ++g) mx = fmaxf(mx, slog[g]);
    float den = 0.f;
    #pragma unroll
    for (int g = 0; g < 8; ++g) den += expf(slog[g] - mx);
    sgate[tid] = expf(slog[tid] - mx) / den;
  }
  __syncthreads();
  float gte = sgate[hh];
  float wa0 = a0 * gte, wa1 = a1 * gte;
  int mt = r >> 7, r8 = (r >> 4) & 7, r15 = r & 15;
  int kg = (j >> 3) & 3, jj = j & 7;
  size_t sub = (size_t)r8*512 + kg*128 + r15*8 + jj;
  size_t b0 = ((size_t)mt*16 + hh*2)     * 4096 + sub;
  size_t b1 = ((size_t)mt*16 + hh*2 + 1) * 4096 + sub;
  _Float16 h0, l0, h1, l1;
  split16(wa0, h0, l0);
  split16(wa1, h1, l1);
  WH[b0] = h0; WL[b0] = l0;
  WH[b1] = h1; WL[b1] = l1;
}

extern "C" void kernel_launch(void* const* d_in, const int* in_sizes, int n_in,
                              void* d_out, int out_size, void* d_ws, size_t ws_size,
                              hipStream_t stream) {
  const float* h_   = (const float*)d_in[0];
  const float* Wr   = (const float*)d_in[1];
  const float* Wi   = (const float*)d_in[2];
  const float* pw1  = (const float*)d_in[3];
  const float* pb1  = (const float*)d_in[4];
  const float* pw2  = (const float*)d_in[5];
  const float* pb2  = (const float*)d_in[6];
  const float* mr   = (const float*)d_in[7];
  const float* mi   = (const float*)d_in[8];
  const float* vals = (const float*)d_in[9];
  const float* gw   = (const float*)d_in[10];
  const float* gb   = (const float*)d_in[11];
  const float* ow   = (const float*)d_in[12];
  const float* ob   = (const float*)d_in[13];

  if (ws_size < WS_FLOATS * sizeof(float)) return;

  float* ws   = (float*)d_ws;
  float* OVL  = ws + OFF_OVL;
  float* HID  = ws + OFF_HID;
  float* n2a  = ws + OFF_N2;
  float* n2b  = ws + OFF_MRE;          // alias: mReN/mImN dead after k_prep_aov16
  float* VG   = ws + OFF_VG;
  float* mReN = ws + OFF_MRE;
  float* mImN = ws + OFF_MIM;
  _Float16* VWH = (_Float16*)(ws + OFF_VWH);
  _Float16* VWL = (_Float16*)(ws + OFF_VWL);
  _Float16* BH  = (_Float16*)(ws + OFF_BH);
  _Float16* BL  = (_Float16*)(ws + OFF_BL);
  _Float16* AH  = (_Float16*)(ws + OFF_AH);
  _Float16* AL  = (_Float16*)(ws + OFF_AL);
  _Float16* WH  = (_Float16*)(ws + OFF_AH);  // alias: A dead after k_qval
  _Float16* WL  = (_Float16*)(ws + OFF_AL);

  k_prep_mem<<<512, 64, 0, stream>>>(mr, mi, mReN, mImN);
  k_prep_vg<<<512, 256, 0, stream>>>(vals, gw, VG);
  k_prep_b16<<<1088, 256, 0, stream>>>(Wr, Wi, pw1, BH, BL);
  k_prep_aov16<<<256, 256, 0, stream>>>(Wr, Wi, mReN, mImN, BH, BL);
  k_gemm64<<<dim3(16, 8), 256, 0, stream>>>(vals, ow, 1024, 1024, 1024, VWH, VWL);
  k_convA<<<4096, 256, 0, stream>>>(h_, 1024, 32, AH, AL);
  k_qnorm<<<2048, 256, 0, stream>>>(AH, BH, n2a, n2b);
  k_qval<<<1152, 256, 0, stream>>>(AH, AL, BH, BL, OVL, HID);
  k_attn<<<ROWS, 256, 0, stream>>>(OVL, HID, n2a, n2b, VG, pb1, pw2, pb2, gb, WH, WL);
  k_fin<<<dim3(8, 128), 256, 0, stream>>>(WH, WL, VWH, VWL, ob, (float*)d_out);
}

// Round 10
// 454.094 us; speedup vs baseline: 1.1207x; 1.0553x over previous
//
#include <hip/hip_runtime.h>
#include <hip/hip_bf16.h>
#include <math.h>

#define ROWS 16384   // B*N = 8*2048

typedef _Float16 f16x8 __attribute__((ext_vector_type(8)));
typedef float f32x4 __attribute__((ext_vector_type(4)));

// ---- workspace offsets (floats); total identical to proven 31,330,304 ----
static const size_t OFF_OVL = 0;            // 16384*512 fp32 overlap
static const size_t OFF_HID = 8388608;      // 16384*128 fp32
static const size_t OFF_N2  = 10485760;     // 16384*8  (n2a)
static const size_t OFF_VG  = 10616832;     // 512*8
static const size_t OFF_MRE = 10620928;     // 65536 (mReN; later n2b low half)
static const size_t OFF_MIM = 10686464;     // 65536 (mImN; later n2b high half)
static const size_t OFF_VWH = 10752000;     // 512*1024 f16 = 262144 fl
static const size_t OFF_VWL = 11014144;     // 262144 fl
static const size_t OFF_BH  = 11276288;     // 1024*3200 f16 = 1638400 fl
static const size_t OFF_BL  = 12914688;     // 1638400 fl
static const size_t OFF_AH  = 14553088;     // 16384*1024 f16 = 8388608 fl; late: WH alias
static const size_t OFF_AL  = 22941696;     // 8388608 fl; late: WL alias
static const size_t WS_FLOATS = 31330304;   // 125.32 MB

__device__ __forceinline__ void gload_lds16(const void* g, void* l) {
  __builtin_amdgcn_global_load_lds((const __attribute__((address_space(1))) void*)g,
                                   (__attribute__((address_space(3))) void*)l, 16, 0, 0);
}

__device__ __forceinline__ void split16(float v, _Float16& hi, _Float16& lo) {
  _Float16 h = (_Float16)v;
  hi = h;
  lo = (_Float16)(v - (float)h);
}

// ---------------- prep: normalize memory states ----------------
__global__ void k_prep_mem(const float* __restrict__ mr, const float* __restrict__ mi,
                           float* __restrict__ mReN, float* __restrict__ mImN) {
  int hs = blockIdx.x;
  int t  = threadIdx.x;
  const float* pr = mr + (size_t)hs * 128;
  const float* pi = mi + (size_t)hs * 128;
  float a0 = pr[t], a1 = pr[t + 64], b0 = pi[t], b1 = pi[t + 64];
  float ss = a0*a0 + a1*a1 + b0*b0 + b1*b1;
  #pragma unroll
  for (int off = 1; off < 64; off <<= 1) ss += __shfl_xor(ss, off);
  float inv = 1.f / fmaxf(sqrtf(ss), 1e-12f);
  mReN[(size_t)hs*128 + t]      = a0 * inv;
  mReN[(size_t)hs*128 + t + 64] = a1 * inv;
  mImN[(size_t)hs*128 + t]      = b0 * inv;
  mImN[(size_t)hs*128 + t + 64] = b1 * inv;
}

// ---------------- prep: VG[h,s,g] ----------------
__global__ __launch_bounds__(256) void k_prep_vg(const float* __restrict__ vals,
                                                 const float* __restrict__ gw,
                                                 float* __restrict__ VG) {
  int hs = blockIdx.x;
  int h  = hs >> 6;
  int t  = threadIdx.x;
  float acc[8] = {0,0,0,0,0,0,0,0};
  for (int dd = t; dd < 1024; dd += 256) {
    float v = vals[(size_t)hs*1024 + dd];
    const float* g = gw + (size_t)(h*1024 + dd)*8;
    #pragma unroll
    for (int q = 0; q < 8; ++q) acc[q] += v * g[q];
  }
  #pragma unroll
  for (int off = 1; off < 64; off <<= 1)
    #pragma unroll
    for (int q = 0; q < 8; ++q) acc[q] += __shfl_xor(acc[q], off);
  __shared__ float red[4][8];
  if ((t & 63) == 0) {
    #pragma unroll
    for (int q = 0; q < 8; ++q) red[t >> 6][q] = acc[q];
  }
  __syncthreads();
  if (t < 8) VG[(size_t)hs*8 + t] = red[0][t] + red[1][t] + red[2][t] + red[3][t];
}

// ---------------- prep: Wr/Wi/pw1 -> BH/BL fragment tiles directly ----------------
__global__ __launch_bounds__(256) void k_prep_b16(const float* __restrict__ Wr,
                                                  const float* __restrict__ Wi,
                                                  const float* __restrict__ pw1,
                                                  _Float16* __restrict__ BH,
                                                  _Float16* __restrict__ BL) {
  int g = blockIdx.x * 256 + threadIdx.x;   // 128*2176 = 278528 total
  int c  = g % 2176;
  int k0 = g / 2176;                        // 0..127 (8 consecutive k)
  float v[8];
  if (c < 1024) {
    int h = c >> 7, e = c & 127;
    const float* p = Wr + ((size_t)(h << 10) + k0*8) * 128 + e;
    #pragma unroll
    for (int j = 0; j < 8; ++j) v[j] = p[(size_t)j*128];
  } else if (c < 2048) {
    int c2 = c - 1024; int h = c2 >> 7, e = c2 & 127;
    const float* p = Wi + ((size_t)(h << 10) + k0*8) * 128 + e;
    #pragma unroll
    for (int j = 0; j < 8; ++j) v[j] = p[(size_t)j*128];
  } else {
    int q = c - 2048; int h = q >> 4, kk = q & 15;
    const float* p = pw1 + ((size_t)(h << 10) + k0*8) * 16 + kk;
    #pragma unroll
    for (int j = 0; j < 8; ++j) v[j] = p[(size_t)j*16];
  }
  int Bcol = (c < 2048) ? c : 3072 + (c - 2048);
  int nt = Bcol >> 7, c8 = (Bcol >> 4) & 7, c15 = Bcol & 15;
  int kt = k0 >> 2, kg = k0 & 3;
  size_t base = ((size_t)nt*32 + kt)*4096 + c8*512 + kg*128 + c15*8;
  f16x8 hv, lv;
  #pragma unroll
  for (int j = 0; j < 8; ++j) { _Float16 hi, lo; split16(v[j], hi, lo); hv[j] = hi; lv[j] = lo; }
  *(f16x8*)(BH + base) = hv;
  *(f16x8*)(BL + base) = lv;
}

// ---------------- prep: Aov -> BH/BL fragment tiles (nt 16..23) ----------------
__global__ __launch_bounds__(256) void k_prep_aov16(const float* __restrict__ Wr,
                                                    const float* __restrict__ Wi,
                                                    const float* __restrict__ mReN,
                                                    const float* __restrict__ mImN,
                                                    _Float16* __restrict__ BH,
                                                    _Float16* __restrict__ BL) {
  int bid = blockIdx.x;          // h(8) x kt64(16) x shalf(2)
  int h   = bid >> 5;
  int kt64 = (bid >> 1) & 15;
  int sh  = bid & 1;
  __shared__ float sRe[32][129];
  __shared__ float sIm[32][129];
  int tid = threadIdx.x;
  int s0 = sh * 32;
  for (int i = tid; i < 32 * 32; i += 256) {
    int s = i >> 5; int e4 = (i & 31) << 2;
    *(float4*)&sRe[s][e4] = *(const float4*)(mReN + ((size_t)(h*64 + s0 + s)*128 + e4));
    *(float4*)&sIm[s][e4] = *(const float4*)(mImN + ((size_t)(h*64 + s0 + s)*128 + e4));
  }
  __syncthreads();
  int kq = tid >> 5;
  int s  = tid & 31;
  int kbase = kt64*64 + kq*8;
  float aR[8] = {0,0,0,0,0,0,0,0}, aI[8] = {0,0,0,0,0,0,0,0};
  for (int e0 = 0; e0 < 128; e0 += 4) {
    float4 mre = *(float4*)&sRe[s][e0];
    float4 mim = *(float4*)&sIm[s][e0];
    #pragma unroll
    for (int j = 0; j < 8; ++j) {
      const float4 wr = *(const float4*)(Wr + ((size_t)(h*1024 + kbase + j))*128 + e0);
      const float4 wi = *(const float4*)(Wi + ((size_t)(h*1024 + kbase + j))*128 + e0);
      aR[j] += wr.x*mre.x + wr.y*mre.y + wr.z*mre.z + wr.w*mre.w
             + wi.x*mim.x + wi.y*mim.y + wi.z*mim.z + wi.w*mim.w;
      aI[j] += wi.x*mre.x + wi.y*mre.y + wi.z*mre.z + wi.w*mre.w
             - (wr.x*mim.x + wr.y*mim.y + wr.z*mim.z + wr.w*mim.w);
    }
  }
  int kt32 = kbase >> 5;
  int kg   = (kbase >> 3) & 3;
  int coln = s0 + s;
  size_t baseR = ((size_t)(16 + h)*32 + kt32)*4096 + (size_t)(coln >> 4)*512 + kg*128 + (coln & 15)*8;
  size_t baseI = baseR + 4*512;
  f16x8 hR, lR, hI, lI;
  #pragma unroll
  for (int j = 0; j < 8; ++j) {
    _Float16 hi, lo;
    split16(aR[j], hi, lo); hR[j] = hi; lR[j] = lo;
    split16(aI[j], hi, lo); hI[j] = hi; lI[j] = lo;
  }
  *(f16x8*)(BH + baseR) = hR; *(f16x8*)(BL + baseR) = lR;
  *(f16x8*)(BH + baseI) = hI; *(f16x8*)(BL + baseI) = lI;
}

// ---------------- VW = values_flat(512x1024) @ out_w(1024x1024) -> VWH/VWL fragment tiles ----------------
__global__ __launch_bounds__(256) void k_gemm64(const float* __restrict__ A,
                                                const float* __restrict__ B,
                                                int K, int lda, int ldb,
                                                _Float16* __restrict__ dh,
                                                _Float16* __restrict__ dl) {
  __shared__ float As[16][64];
  __shared__ float Bs[16][64];
  int tid = threadIdx.x;
  int tm = tid >> 4, tn = tid & 15;
  float acc[4][4];
  #pragma unroll
  for (int i = 0; i < 4; ++i)
    #pragma unroll
    for (int j = 0; j < 4; ++j) acc[i][j] = 0.f;
  int row0 = blockIdx.y << 6, col0 = blockIdx.x << 6;
  int ar = tid >> 2, ak = (tid & 3) << 2;
  int bkr = tid >> 4, bc = (tid & 15) << 2;
  for (int kt = 0; kt < K; kt += 16) {
    float4 a0 = *(const float4*)(A + (size_t)(row0 + ar)*lda + kt + ak);
    float4 b0 = *(const float4*)(B + (size_t)(kt + bkr)*ldb + col0 + bc);
    __syncthreads();
    As[ak+0][ar] = a0.x; As[ak+1][ar] = a0.y; As[ak+2][ar] = a0.z; As[ak+3][ar] = a0.w;
    *(float4*)&Bs[bkr][bc] = b0;
    __syncthreads();
    #pragma unroll
    for (int k = 0; k < 16; ++k) {
      float af[4], bf[4];
      *(float4*)&af[0] = *(const float4*)&As[k][tm << 2];
      *(float4*)&bf[0] = *(const float4*)&Bs[k][tn << 2];
      #pragma unroll
      for (int i = 0; i < 4; ++i)
        #pragma unroll
        for (int j = 0; j < 4; ++j) acc[i][j] += af[i] * bf[j];
    }
  }
  // write B-side fragment tiles directly (k-dim 512 -> 16 k-tiles for k_fin)
  #pragma unroll
  for (int i = 0; i < 4; ++i) {
    int row = row0 + (tm << 2) + i;            // k-dim 0..511
    int ktl = row >> 5, kg = (row >> 3) & 3, jj = row & 7;
    #pragma unroll
    for (int j = 0; j < 4; ++j) {
      int col = col0 + (tn << 2) + j;          // 0..1023
      int nt = col >> 7, c8 = (col >> 4) & 7, c15 = col & 15;
      size_t base = ((size_t)nt*16 + ktl)*4096 + c8*512 + kg*128 + c15*8 + jj;
      _Float16 hi, lo; split16(acc[i][j], hi, lo);
      dh[base] = hi; dl[base] = lo;
    }
  }
}

// ---------------- convA: row-major fp32 -> hi/lo f16 fragment tiles (round-4 proven) ----------------
__global__ __launch_bounds__(256) void k_convA(const float* __restrict__ src, int lda, int ktiles,
                                               _Float16* __restrict__ dh, _Float16* __restrict__ dl) {
  int mt = blockIdx.x / ktiles, kt = blockIdx.x % ktiles;
  size_t base = (size_t)blockIdx.x * 4096;
  for (int q = 0; q < 16; ++q) {
    int i = q*256 + threadIdx.x;
    int r8 = i >> 9, kg = (i >> 7) & 3, r15 = (i >> 3) & 15, j = i & 7;
    int row = mt*128 + r8*16 + r15;
    int k   = kt*32 + kg*8 + j;
    float v = src[(size_t)row*lda + k];
    _Float16 hi, lo; split16(v, hi, lo);
    dh[base + i] = hi; dl[base + i] = lo;
  }
}

// ---------------- norm GEMM: hi-only, 128x128, double-buffered; n2a (XR) / n2b (XI), LDS wc-combine ----------------
__global__ __launch_bounds__(256) void k_qnorm(const _Float16* __restrict__ Ah,
                                               const _Float16* __restrict__ Bh,
                                               float* __restrict__ n2a,
                                               float* __restrict__ n2b) {
  __shared__ __align__(16) char smem[32768];
  const int id = blockIdx.x;
  const int by = (id & 7) * 16 + ((id >> 3) & 15);
  const int bx = id >> 7;                      // 0..15
  const int tid = threadIdx.x;
  const int wid = tid >> 6, lane = tid & 63;
  const int wr = wid >> 1, wc = wid & 1;
  const char* gA = (const char*)Ah + (size_t)by * 32 * 8192;
  const char* gB = (const char*)Bh + (size_t)bx * 32 * 8192;

  f32x4 acc[4][4];
  #pragma unroll
  for (int i = 0; i < 4; ++i)
    #pragma unroll
    for (int j = 0; j < 4; ++j) acc[i][j] = (f32x4){0.f,0.f,0.f,0.f};

  auto stage = [&](int b, int kt) {
    const char* srcA = gA + (size_t)kt * 8192;
    const char* srcB = gB + (size_t)kt * 8192;
    char* dA = smem + b * 8192;
    char* dB = smem + 16384 + b * 8192;
    #pragma unroll
    for (int q = 0; q < 4; ++q) {
      int c = wid * 4 + q;
      int sub = (c & 7) * 1024;
      if (c < 8) gload_lds16(srcA + sub + lane*16, dA + sub);
      else       gload_lds16(srcB + sub + lane*16, dB + sub);
    }
  };

  stage(0, 0);
  asm volatile("s_waitcnt vmcnt(0)" ::: "memory");
  __builtin_amdgcn_s_barrier();
  int cur = 0;
  for (int kt = 0; kt < 32; ++kt) {
    if (kt < 31) stage(cur ^ 1, kt + 1);
    const char* cA = smem + cur * 8192;
    const char* cB = smem + 16384 + cur * 8192;
    f16x8 a[4], b[4];
    #pragma unroll
    for (int m = 0; m < 4; ++m) a[m] = *(const f16x8*)(cA + wr*4096 + m*1024 + lane*16);
    #pragma unroll
    for (int n = 0; n < 4; ++n) b[n] = *(const f16x8*)(cB + wc*4096 + n*1024 + lane*16);
    #pragma unroll
    for (int m = 0; m < 4; ++m)
      #pragma unroll
      for (int n = 0; n < 4; ++n)
        acc[m][n] = __builtin_amdgcn_mfma_f32_16x16x32_f16(a[m], b[n], acc[m][n], 0, 0, 0);
    if (kt < 31) {
      asm volatile("s_waitcnt vmcnt(0)" ::: "memory");
      __builtin_amdgcn_s_barrier();
    }
    cur ^= 1;
  }

  // per-row partial (64 cols per wc wave), then combine across wc via LDS
  float rsv[16];
  #pragma unroll
  for (int m = 0; m < 4; ++m)
    #pragma unroll
    for (int rr = 0; rr < 4; ++rr) {
      float rs = 0.f;
      #pragma unroll
      for (int n = 0; n < 4; ++n) rs += acc[m][n][rr] * acc[m][n][rr];
      rs += __shfl_xor(rs, 1); rs += __shfl_xor(rs, 2);
      rs += __shfl_xor(rs, 4); rs += __shfl_xor(rs, 8);
      rsv[m*4 + rr] = rs;
    }
  __syncthreads();                 // LDS staging buffers now dead
  float* scomb = (float*)smem;     // [128] per-row partial from wc=0
  if (wc == 0) {
    #pragma unroll
    for (int m = 0; m < 4; ++m)
      #pragma unroll
      for (int rr = 0; rr < 4; ++rr)
        if ((lane & 15) == 0)
          scomb[wr*64 + m*16 + (lane >> 4)*4 + rr] = rsv[m*4 + rr];
  }
  __syncthreads();
  if (wc == 1) {
    const int head = bx & 7;
    float* dst = (bx < 8) ? n2a : n2b;
    #pragma unroll
    for (int m = 0; m < 4; ++m)
      #pragma unroll
      for (int rr = 0; rr < 4; ++rr)
        if ((lane & 15) == 0) {
          int r128 = wr*64 + m*16 + (lane >> 4)*4 + rr;
          dst[(size_t)(by*128 + r128)*8 + head] = rsv[m*4 + rr] + scomb[r128];
        }
  }
}

// ---------------- value GEMM: 3-term, 128x128, double-buffered (bx<8: OV head, bx==8: HID) ----------------
__global__ __launch_bounds__(256) void k_qval(const _Float16* __restrict__ Ah,
                                              const _Float16* __restrict__ Al,
                                              const _Float16* __restrict__ Bh,
                                              const _Float16* __restrict__ Bl,
                                              float* __restrict__ OVL,
                                              float* __restrict__ HID) {
  __shared__ __align__(16) char smem[65536];   // 2 bufs x {Ah,Al,Bh,Bl} x 8KB
  const int id = blockIdx.x;
  const int rest = id >> 3;
  const int by = (id & 7) * 16 + (rest & 15);
  const int bx = rest >> 4;                    // 0..8
  const int tid = threadIdx.x;
  const int wid = tid >> 6, lane = tid & 63;
  const int wr = wid >> 1, wc = wid & 1;
  f32x4 acc[4][4];
  #pragma unroll
  for (int i = 0; i < 4; ++i)
    #pragma unroll
    for (int j = 0; j < 4; ++j) acc[i][j] = (f32x4){0.f,0.f,0.f,0.f};

  const char* pAh = (const char*)Ah + (size_t)by*32*8192;
  const char* pAl = (const char*)Al + (size_t)by*32*8192;
  const char* pBh = (const char*)Bh + (size_t)(16 + bx)*32*8192;
  const char* pBl = (const char*)Bl + (size_t)(16 + bx)*32*8192;
  const char* mysrc = (wid == 0) ? pAh : (wid == 1) ? pAl : (wid == 2) ? pBh : pBl;

  auto stage = [&](int b, int kt) {
    const char* s = mysrc + (size_t)kt*8192 + lane*16;
    char* d = smem + b*32768 + wid*8192;
    #pragma unroll
    for (int q = 0; q < 8; ++q)
      gload_lds16(s + q*1024, d + q*1024);
  };

  stage(0, 0);
  asm volatile("s_waitcnt vmcnt(0)" ::: "memory");
  __builtin_amdgcn_s_barrier();
  int cur = 0;
  for (int kt = 0; kt < 32; ++kt) {
    if (kt < 31) stage(cur ^ 1, kt + 1);
    const char* base = smem + cur*32768;
    const char* cAh = base;
    const char* cAl = base + 8192;
    const char* cBh = base + 16384;
    const char* cBl = base + 24576;
    f16x8 a_h[4], a_l[4], b_h[4], b_l[4];
    #pragma unroll
    for (int m = 0; m < 4; ++m) { a_h[m] = *(const f16x8*)(cAh + wr*4096 + m*1024 + lane*16);
                                  a_l[m] = *(const f16x8*)(cAl + wr*4096 + m*1024 + lane*16); }
    #pragma unroll
    for (int n = 0; n < 4; ++n) { b_h[n] = *(const f16x8*)(cBh + wc*4096 + n*1024 + lane*16);
                                  b_l[n] = *(const f16x8*)(cBl + wc*4096 + n*1024 + lane*16); }
    #pragma unroll
    for (int m = 0; m < 4; ++m)
      #pragma unroll
      for (int n = 0; n < 4; ++n) {
        acc[m][n] = __builtin_amdgcn_mfma_f32_16x16x32_f16(a_h[m], b_h[n], acc[m][n], 0, 0, 0);
        acc[m][n] = __builtin_amdgcn_mfma_f32_16x16x32_f16(a_l[m], b_h[n], acc[m][n], 0, 0, 0);
        acc[m][n] = __builtin_amdgcn_mfma_f32_16x16x32_f16(a_h[m], b_l[n], acc[m][n], 0, 0, 0);
      }
    if (kt < 31) {
      asm volatile("s_waitcnt vmcnt(0)" ::: "memory");
      __builtin_amdgcn_s_barrier();
    }
    cur ^= 1;
  }
  __syncthreads();   // all waves done with LDS buffers before epilogue reuse

  if (bx == 8) {
    #pragma unroll
    for (int m = 0; m < 4; ++m)
      #pragma unroll
      for (int n = 0; n < 4; ++n)
        #pragma unroll
        for (int rr = 0; rr < 4; ++rr) {
          int row = by*128 + wr*64 + m*16 + (lane>>4)*4 + rr;
          int col = wc*64 + n*16 + (lane&15);
          HID[(size_t)row*128 + col] = acc[m][n][rr];
        }
  } else {
    float* sOv = (float*)smem;   // [128][68]
    if (wc == 0) {
      #pragma unroll
      for (int m = 0; m < 4; ++m)
        #pragma unroll
        for (int n = 0; n < 4; ++n)
          #pragma unroll
          for (int rr = 0; rr < 4; ++rr) {
            int r128 = wr*64 + m*16 + (lane>>4)*4 + rr;
            int s = n*16 + (lane&15);
            sOv[r128*68 + s] = acc[m][n][rr]*acc[m][n][rr];
          }
    }
    __syncthreads();
    if (wc == 1) {
      #pragma unroll
      for (int m = 0; m < 4; ++m)
        #pragma unroll
        for (int n = 0; n < 4; ++n)
          #pragma unroll
          for (int rr = 0; rr < 4; ++rr) {
            int r128 = wr*64 + m*16 + (lane>>4)*4 + rr;
            int s = n*16 + (lane&15);
            float v = sOv[r128*68 + s] + acc[m][n][rr]*acc[m][n][rr];
            int row = by*128 + r128;
            OVL[(size_t)row*512 + bx*64 + s] = v;
          }
    }
  }
}

// ---------------- final MFMA GEMM: double-buffered; out = wattn(16384x512) @ VW(512x1024) + out_b ----------------
__global__ __launch_bounds__(256) void k_fin(const _Float16* __restrict__ Ahh,
                                             const _Float16* __restrict__ Alo,
                                             const _Float16* __restrict__ Bhh,
                                             const _Float16* __restrict__ Blo,
                                             const float* __restrict__ bias,
                                             float* __restrict__ out) {
  __shared__ __align__(16) char smem[65536];   // 2 bufs x {Ah,Al,Bh,Bl} x 8KB
  const int id = blockIdx.x;                   // 1024: XCD-partitioned decode
  const int by = (id & 7) * 16 + ((id >> 3) & 15);   // 0..127
  const int bx = id >> 7;                      // 0..7
  const int tid = threadIdx.x;
  const int wid = tid >> 6, lane = tid & 63;
  const int wr = wid >> 1, wc = wid & 1;
  f32x4 acc[4][4];
  #pragma unroll
  for (int i = 0; i < 4; ++i)
    #pragma unroll
    for (int j = 0; j < 4; ++j) acc[i][j] = (f32x4){0.f,0.f,0.f,0.f};
  const char* pAh = (const char*)Ahh + (size_t)by*16*8192;
  const char* pAl = (const char*)Alo + (size_t)by*16*8192;
  const char* pBh = (const char*)Bhh + (size_t)bx*16*8192;
  const char* pBl = (const char*)Blo + (size_t)bx*16*8192;
  const char* mysrc = (wid == 0) ? pAh : (wid == 1) ? pAl : (wid == 2) ? pBh : pBl;

  auto stage = [&](int b, int kt) {
    const char* s = mysrc + (size_t)kt*8192 + lane*16;
    char* d = smem + b*32768 + wid*8192;
    #pragma unroll
    for (int q = 0; q < 8; ++q)
      gload_lds16(s + q*1024, d + q*1024);
  };

  stage(0, 0);
  asm volatile("s_waitcnt vmcnt(0)" ::: "memory");
  __builtin_amdgcn_s_barrier();
  int cur = 0;
  for (int kt = 0; kt < 16; ++kt) {
    if (kt < 15) stage(cur ^ 1, kt + 1);
    const char* base = smem + cur*32768;
    const char* cAh = base;
    const char* cAl = base + 8192;
    const char* cBh = base + 16384;
    const char* cBl = base + 24576;
    f16x8 a_h[4], a_l[4], b_h[4], b_l[4];
    #pragma unroll
    for (int m = 0; m < 4; ++m) { a_h[m] = *(const f16x8*)(cAh + wr*4096 + m*1024 + lane*16);
                                  a_l[m] = *(const f16x8*)(cAl + wr*4096 + m*1024 + lane*16); }
    #pragma unroll
    for (int n = 0; n < 4; ++n) { b_h[n] = *(const f16x8*)(cBh + wc*4096 + n*1024 + lane*16);
                                  b_l[n] = *(const f16x8*)(cBl + wc*4096 + n*1024 + lane*16); }
    #pragma unroll
    for (int m = 0; m < 4; ++m)
      #pragma unroll
      for (int n = 0; n < 4; ++n) {
        acc[m][n] = __builtin_amdgcn_mfma_f32_16x16x32_f16(a_h[m], b_h[n], acc[m][n], 0, 0, 0);
        acc[m][n] = __builtin_amdgcn_mfma_f32_16x16x32_f16(a_l[m], b_h[n], acc[m][n], 0, 0, 0);
        acc[m][n] = __builtin_amdgcn_mfma_f32_16x16x32_f16(a_h[m], b_l[n], acc[m][n], 0, 0, 0);
      }
    if (kt < 15) {
      asm volatile("s_waitcnt vmcnt(0)" ::: "memory");
      __builtin_amdgcn_s_barrier();
    }
    cur ^= 1;
  }
  #pragma unroll
  for (int m = 0; m < 4; ++m)
    #pragma unroll
    for (int n = 0; n < 4; ++n) {
      int col = bx*128 + wc*64 + n*16 + (lane&15);
      float bv = bias[col];
      #pragma unroll
      for (int rr = 0; rr < 4; ++rr) {
        int row = by*128 + wr*64 + m*16 + (lane>>4)*4 + rr;
        out[(size_t)row*1024 + col] = acc[m][n][rr] + bv;
      }
    }
}

// ---------------- per-row attention, wave-per-row (4 rows/block, no barriers/LDS) ----------------
__global__ __launch_bounds__(256) void k_attn(const float* __restrict__ OVL,
                                              const float* __restrict__ HID,
                                              const float* __restrict__ n2a,
                                              const float* __restrict__ n2b,
                                              const float* __restrict__ VG,
                                              const float* __restrict__ pb1,
                                              const float* __restrict__ pw2,
                                              const float* __restrict__ pb2,
                                              const float* __restrict__ gb,
                                              _Float16* __restrict__ WH,
                                              _Float16* __restrict__ WL) {
  const int wid = threadIdx.x >> 6;
  const int lane = threadIdx.x & 63;
  const int r = blockIdx.x * 4 + wid;          // one wave per row
  const int h = lane >> 3;                     // head 0..7 (8 lanes each)
  const int sub = lane & 7;                    // 8 s-values per lane: s = sub*8..sub*8+7
  // load overlaps (contiguous 8 floats)
  const float* ovp = OVL + (size_t)r*512 + h*64 + sub*8;
  float4 o0 = *(const float4*)ovp;
  float4 o1 = *(const float4*)(ovp + 4);
  float ov[8] = {o0.x, o0.y, o0.z, o0.w, o1.x, o1.y, o1.z, o1.w};
  // decoherence prob p: lane covers hidden units kk = sub*2, sub*2+1
  float z = 0.f;
  #pragma unroll
  for (int t = 0; t < 2; ++t) {
    int kk = sub*2 + t;
    float x = HID[(size_t)r*128 + h*16 + kk] + pb1[h*16 + kk];
    float sg = 1.f / (1.f + expf(-x));
    z += x * sg * pw2[h*16 + kk];
  }
  z += __shfl_xor(z, 1); z += __shfl_xor(z, 2); z += __shfl_xor(z, 4);
  z += pb2[h];
  float p = 0.95f / (1.f + expf(-z));
  float nn = n2a[(size_t)r*8 + h] + n2b[(size_t)r*8 + h];
  float inv_n2 = 1.f / fmaxf(nn, 1e-24f);
  float base = (1.f - p) * 0.0078125f;   // (1-p)/128
  float rw[8];
  float rsum = 0.f;
  #pragma unroll
  for (int q = 0; q < 8; ++q) { rw[q] = p * (ov[q] * inv_n2) + base; rsum += rw[q]; }
  rsum += __shfl_xor(rsum, 1); rsum += __shfl_xor(rsum, 2); rsum += __shfl_xor(rsum, 4);
  float inv_den = 1.f / (rsum + 1e-8f);
  float a[8];
  #pragma unroll
  for (int q = 0; q < 8; ++q) a[q] = rw[q] * inv_den;
  // gate logits: lg[g] = sum over all 512 s of a_s * VG[s,g]
  float lg[8] = {0,0,0,0,0,0,0,0};
  const float* vgp = VG + (size_t)(h*64 + sub*8) * 8;
  #pragma unroll
  for (int q = 0; q < 8; ++q)
    #pragma unroll
    for (int g = 0; g < 8; ++g) lg[g] += a[q] * vgp[q*8 + g];
  #pragma unroll
  for (int off = 1; off < 64; off <<= 1)
    #pragma unroll
    for (int g = 0; g < 8; ++g) lg[g] += __shfl_xor(lg[g], off);
  float lt[8];
  #pragma unroll
  for (int g = 0; g < 8; ++g) lt[g] = lg[g] + gb[g];
  float mx = lt[0];
  #pragma unroll
  for (int g = 1; g < 8; ++g) mx = fmaxf(mx, lt[g]);
  float den = 0.f;
  #pragma unroll
  for (int g = 0; g < 8; ++g) den += expf(lt[g] - mx);
  float gate = expf(lt[h] - mx) / den;
  // fragment write: 8 contiguous slots (kg = sub&3, j = 0..7), kt-tile = h*2 + (sub>=4)
  int mt = r >> 7, r8 = (r >> 4) & 7, r15 = r & 15;
  size_t basek = ((size_t)mt*16 + h*2 + (sub >> 2)) * 4096
               + (size_t)r8*512 + (size_t)(sub & 3)*128 + (size_t)r15*8;
  f16x8 hv, lv;
  #pragma unroll
  for (int q = 0; q < 8; ++q) {
    _Float16 hi, lo;
    split16(a[q] * gate, hi, lo);
    hv[q] = hi; lv[q] = lo;
  }
  *(f16x8*)(WH + basek) = hv;
  *(f16x8*)(WL + basek) = lv;
}

extern "C" void kernel_launch(void* const* d_in, const int* in_sizes, int n_in,
                              void* d_out, int out_size, void* d_ws, size_t ws_size,
                              hipStream_t stream) {
  const float* h_   = (const float*)d_in[0];
  const float* Wr   = (const float*)d_in[1];
  const float* Wi   = (const float*)d_in[2];
  const float* pw1  = (const float*)d_in[3];
  const float* pb1  = (const float*)d_in[4];
  const float* pw2  = (const float*)d_in[5];
  const float* pb2  = (const float*)d_in[6];
  const float* mr   = (const float*)d_in[7];
  const float* mi   = (const float*)d_in[8];
  const float* vals = (const float*)d_in[9];
  const float* gw   = (const float*)d_in[10];
  const float* gb   = (const float*)d_in[11];
  const float* ow   = (const float*)d_in[12];
  const float* ob   = (const float*)d_in[13];

  if (ws_size < WS_FLOATS * sizeof(float)) return;

  float* ws   = (float*)d_ws;
  float* OVL  = ws + OFF_OVL;
  float* HID  = ws + OFF_HID;
  float* n2a  = ws + OFF_N2;
  float* n2b  = ws + OFF_MRE;          // alias: mReN/mImN dead after k_prep_aov16
  float* VG   = ws + OFF_VG;
  float* mReN = ws + OFF_MRE;
  float* mImN = ws + OFF_MIM;
  _Float16* VWH = (_Float16*)(ws + OFF_VWH);
  _Float16* VWL = (_Float16*)(ws + OFF_VWL);
  _Float16* BH  = (_Float16*)(ws + OFF_BH);
  _Float16* BL  = (_Float16*)(ws + OFF_BL);
  _Float16* AH  = (_Float16*)(ws + OFF_AH);
  _Float16* AL  = (_Float16*)(ws + OFF_AL);
  _Float16* WH  = (_Float16*)(ws + OFF_AH);  // alias: A dead after k_qval
  _Float16* WL  = (_Float16*)(ws + OFF_AL);

  k_prep_mem<<<512, 64, 0, stream>>>(mr, mi, mReN, mImN);
  k_prep_vg<<<512, 256, 0, stream>>>(vals, gw, VG);
  k_prep_b16<<<1088, 256, 0, stream>>>(Wr, Wi, pw1, BH, BL);
  k_prep_aov16<<<256, 256, 0, stream>>>(Wr, Wi, mReN, mImN, BH, BL);
  k_gemm64<<<dim3(16, 8), 256, 0, stream>>>(vals, ow, 1024, 1024, 1024, VWH, VWL);
  k_convA<<<4096, 256, 0, stream>>>(h_, 1024, 32, AH, AL);
  k_qnorm<<<2048, 256, 0, stream>>>(AH, BH, n2a, n2b);
  k_qval<<<1152, 256, 0, stream>>>(AH, AL, BH, BL, OVL, HID);
  k_attn<<<4096, 256, 0, stream>>>(OVL, HID, n2a, n2b, VG, pb1, pw2, pb2, gb, WH, WL);
  k_fin<<<1024, 256, 0, stream>>>(WH, WL, VWH, VWL, ob, (float*)d_out);
}